// Round 10
// baseline (613.190 us; speedup 1.0000x reference)
//
#include <hip/hip_runtime.h>

typedef unsigned short u16;
typedef short bf16x8 __attribute__((ext_vector_type(8)));
typedef float f32x4 __attribute__((ext_vector_type(4)));

__device__ __forceinline__ float bf2f(u16 s) {
    union { unsigned u; float f; } v;
    v.u = ((unsigned)s) << 16;
    return v.f;
}
__device__ __forceinline__ u16 f2bf(float f) {
    union { float f; unsigned u; } v;
    v.f = f;
    unsigned r = v.u + 0x7fffu + ((v.u >> 16) & 1u);  // RNE
    return (u16)(r >> 16);
}

#define GLD16(gp, lp)                                                  \
    __builtin_amdgcn_global_load_lds(                                  \
        (__attribute__((address_space(1))) void*)(gp),                 \
        (__attribute__((address_space(3))) void*)(lp), 16, 0, 0)

#define CFENCE asm volatile("" ::: "memory")
#define BARRIER __builtin_amdgcn_s_barrier()

// ---------------------------------------------------------------------------
// Detect whether d_in[0] is f32 (flag=1) or bf16 (flag=0).
// ---------------------------------------------------------------------------
__global__ __launch_bounds__(256) void detect_kernel(
    const u16* __restrict__ src, int* __restrict__ flag)
{
    __shared__ int red[4];
    const int tid = threadIdx.x;
    int cnt = 0;
    for (int j = 0; j < 64; j++) {
        const u16 v = src[tid * 64 + j];
        const int e = (v >> 7) & 0xFF;
        cnt += (e >= 0x90) ? 1 : 0;
    }
#pragma unroll
    for (int m = 1; m < 64; m <<= 1) cnt += __shfl_xor(cnt, m);
    if ((tid & 63) == 0) red[tid >> 6] = cnt;
    __syncthreads();
    if (tid == 0) {
        const int total = red[0] + red[1] + red[2] + red[3];
        flag[0] = (total > 1024) ? 1 : 0;
    }
}

// ---------------------------------------------------------------------------
// Single merged conversion: all 15 inputs -> contiguous bf16 region in ws.
// ---------------------------------------------------------------------------
struct ConvArgs {
    const void* src[15];
    long long   off[16];   // cumulative element offsets in dst (off[15]=total)
};

__global__ __launch_bounds__(256) void convert_all_kernel(
    ConvArgs a, u16* __restrict__ dst, const int* __restrict__ flag)
{
    const long long i = ((long long)blockIdx.x * 256 + threadIdx.x) * 8;
    if (i >= a.off[15]) return;
    int s = 0;
#pragma unroll
    for (int t = 1; t < 15; t++) s += (i >= a.off[t]) ? 1 : 0;
    const long long local = i - a.off[s];
    union { uint4 q; u16 u[8]; } o;
    if (flag[0]) {
        const float* sp = (const float*)a.src[s] + local;
        const float4 x = *(const float4*)sp;
        const float4 y = *(const float4*)(sp + 4);
        o.u[0] = f2bf(x.x); o.u[1] = f2bf(x.y);
        o.u[2] = f2bf(x.z); o.u[3] = f2bf(x.w);
        o.u[4] = f2bf(y.x); o.u[5] = f2bf(y.y);
        o.u[6] = f2bf(y.z); o.u[7] = f2bf(y.w);
    } else {
        o.q = *(const uint4*)((const u16*)a.src[s] + local);
    }
    *(uint4*)(dst + i) = o.q;
}

// ---------------------------------------------------------------------------
// 256x256-tile GEMM, 8-phase pipelined schedule (T1+T2+T3+T4+T5).
//   C[M,N](bf16) = scale * (A[M,K] . B[N,K]^T) + bias
// 512 threads = 8 waves (2 M x 4 N), per-wave 128x64 via 8x4 MFMA 16x16x32.
// BK=64, LDS = 2 buffers x (A 32KB + B 32KB) = 128KB -> 1 block/CU.
// Staging: global_load_lds w=16, linear LDS dest, XOR col-block swizzle on
//   the GLOBAL source address (m173 pattern) -> conflict-free ds_read_b128
//   (measured SQ_LDS_BANK_CONFLICT = 0).
// Schedule per iteration (2 K-tiles): 8 phases, each
//   {ds_read quadrant | stage 1 half-tile (2 loads) | bar | setprio(1)
//    16 MFMA setprio(0) | bar};  counted vmcnt(6) at phases 4 & 8 only.
// (lgkmcnt(8) pacing REMOVED: measured regression, QK^T 80->108us,
//  MfmaUtil 34->26% with identical FETCH/WRITE -- the early LDS wait
//  serializes what compiler-placed lgkmcnt(N) already overlapped.)
// dualMode: 1 = {B,bias}->alt when bm>=nbm/2; 2 = {A,bias}->alt when
//   bn>=nbn/2; 3 = 3-way B select: bm>=3*nbm/4 -> alt2, bm>=nbm/2 -> alt.
// bias_mode: 0 none, 1 bias[col], 2 bias[row].
// Batching: zShift>=0 -> z = swizzled_id >> zShift (flattened grid, global
//   XCD swizzle gives per-XCD z locality); else z = blockIdx.z.
//   A += (z & zAmask)*sA, B += z*sB, C += z*sC.
// ---------------------------------------------------------------------------
__global__ __launch_bounds__(512, 2) void gemm256_kernel(
    const u16* __restrict__ A, const u16* __restrict__ B,
    u16* __restrict__ C, const u16* __restrict__ bias,
    const u16* __restrict__ alt, const u16* __restrict__ biasAlt,
    const u16* __restrict__ alt2, const u16* __restrict__ biasAlt2,
    float scale, int bias_mode, int dualMode, int nbnShift, int zAmask,
    int zShift,
    int lda, int ldb, int ldc, int K,
    long long sA, long long sB, long long sC)
{
    __shared__ alignas(16) u16 lds[4][256 * 64];  // [buf*2 + op], 128 KB

    const int tid  = threadIdx.x;
    const int lane = tid & 63;
    const int wave = tid >> 6;
    const int wm   = wave >> 2;      // 0..1
    const int wn   = wave & 3;       // 0..3

    // T1: bijective XCD swizzle (m204) over the full flattened grid
    const int nwg = gridDim.x;
    int id = blockIdx.x;
    if (nwg >= 8) {
        const int q = nwg >> 3, r = nwg & 7;
        const int x = id & 7, sidx = id >> 3;
        id = (x < r ? x * (q + 1) : r * (q + 1) + (x - r) * q) + sidx;
    }
    int z, rem;
    if (zShift >= 0) { z = id >> zShift; rem = id & ((1 << zShift) - 1); }
    else             { z = blockIdx.z;   rem = id; }
    const int nbn = 1 << nbnShift;
    const int bm = rem >> nbnShift, bn = rem & (nbn - 1);
    const int nbm = ((zShift >= 0) ? (1 << zShift) : nwg) >> nbnShift;

    if (dualMode == 1 && bm >= (nbm >> 1)) { B = alt; bias = biasAlt; }
    if (dualMode == 2 && bn >= (nbn >> 1)) { A = alt; bias = biasAlt; }
    if (dualMode == 3) {
        if (bm >= 3 * (nbm >> 2))      { B = alt2; bias = biasAlt2; }
        else if (bm >= (nbm >> 1))     { B = alt;  bias = biasAlt; }
    }

    A += (long long)(z & zAmask) * sA;
    B += (long long)z * sB;
    C += (long long)z * sC;

    // ---- staging addresses (per-lane global, wave-uniform LDS base) ----
    const int rw  = lane >> 3;           // 0..7 row within wave chunk
    const int cb  = lane & 7;            // LDS col-block
    const int scb = cb ^ rw;             // swizzled GLOBAL col-block
    const int srow = wave * 8 + rw;      // 0..63
    const int bRowBase = ((wave & 4) << 4) + ((wave & 3) << 3);

    const u16* aG = A + (long long)(bm * 256 + srow) * lda + scb * 8;
    const u16* bG = B + (long long)(bn * 256 + bRowBase + rw) * ldb + scb * 8;
    const long long a64  = (long long)64 * lda;
    const long long a128 = (long long)128 * lda;
    const long long b32  = (long long)32 * ldb;
    const long long b128 = (long long)128 * ldb;

#define STAGE_A(buf, mh, k0) do {                                         \
        u16* d_ = &lds[(buf) * 2][((mh) * 64 + wave * 8) * 64];           \
        GLD16(aG + (k0) + ((mh) ? a64 : 0), d_);                          \
        GLD16(aG + (k0) + ((mh) ? a64 : 0) + a128, d_ + 128 * 64);        \
    } while (0)
#define STAGE_B(buf, nh, k0) do {                                         \
        u16* d_ = &lds[(buf) * 2 + 1][(bRowBase + (nh) * 32) * 64];       \
        GLD16(bG + (k0) + ((nh) ? b32 : 0), d_);                          \
        GLD16(bG + (k0) + ((nh) ? b32 : 0) + b128, d_ + 128 * 64);        \
    } while (0)

    // ---- fragment read addressing (XOR-unswizzle on read) ----
    const int fr = lane & 15, fq = lane >> 4;
    const int c0 = ((fq ^ (fr & 7)) << 3);
    const int c1 = (((4 | fq) ^ (fr & 7)) << 3);
    const u16* aRd0 = &lds[0][(wm * 128 + fr) * 64];
    const u16* aRd1 = &lds[2][(wm * 128 + fr) * 64];
    const u16* bRd0 = &lds[1][(wn * 64 + fr) * 64];
    const u16* bRd1 = &lds[3][(wn * 64 + fr) * 64];

    bf16x8 aF[4][2], bF0[2][2], bF1[2][2];
    f32x4 acc[8][4];
#pragma unroll
    for (int i = 0; i < 8; i++)
#pragma unroll
        for (int j = 0; j < 4; j++) {
            acc[i][j][0] = 0.f; acc[i][j][1] = 0.f;
            acc[i][j][2] = 0.f; acc[i][j][3] = 0.f;
        }

#define DS_A(base, mh) do {                                               \
        _Pragma("unroll") for (int i_ = 0; i_ < 4; i_++) {                \
            const u16* p_ = (base) + ((mh) * 64 + i_ * 16) * 64;          \
            aF[i_][0] = *(const bf16x8*)(p_ + c0);                        \
            aF[i_][1] = *(const bf16x8*)(p_ + c1);                        \
        } } while (0)
#define DS_B(base, nh, arr) do {                                          \
        _Pragma("unroll") for (int j_ = 0; j_ < 2; j_++) {                \
            const u16* p_ = (base) + ((nh) * 32 + j_ * 16) * 64;          \
            arr[j_][0] = *(const bf16x8*)(p_ + c0);                       \
            arr[j_][1] = *(const bf16x8*)(p_ + c1);                       \
        } } while (0)
#define MFMA_Q(mh, nh, arr) do {                                          \
        __builtin_amdgcn_s_setprio(1);                                    \
        _Pragma("unroll") for (int i_ = 0; i_ < 4; i_++)                  \
        _Pragma("unroll") for (int j_ = 0; j_ < 2; j_++) {                \
            f32x4 v_ = acc[(mh) * 4 + i_][(nh) * 2 + j_];                 \
            v_ = __builtin_amdgcn_mfma_f32_16x16x32_bf16(                 \
                     aF[i_][0], arr[j_][0], v_, 0, 0, 0);                 \
            v_ = __builtin_amdgcn_mfma_f32_16x16x32_bf16(                 \
                     aF[i_][1], arr[j_][1], v_, 0, 0, 0);                 \
            acc[(mh) * 4 + i_][(nh) * 2 + j_] = v_;                       \
        }                                                                 \
        __builtin_amdgcn_s_setprio(0);                                    \
    } while (0)

    const int NT = K >> 6;        // K / 64, assumed even and >= 2
    const int NITER = NT >> 1;

    // ---- prologue: tile0 full -> buf0; tile1 {A-mh0, B-nh0, B-nh1} -> buf1
    STAGE_A(0, 0, 0); STAGE_A(0, 1, 0); STAGE_B(0, 0, 0); STAGE_B(0, 1, 0);
    if (NT > 1) {
        STAGE_A(1, 0, 64); STAGE_B(1, 0, 64); STAGE_B(1, 1, 64);
        asm volatile("s_waitcnt vmcnt(6)" ::: "memory");
    } else {
        asm volatile("s_waitcnt vmcnt(0)" ::: "memory");
    }
    CFENCE; BARRIER; CFENCE;

    for (int it = 0; it < NITER; it++) {
        const int t = it * 2;
        const int k1 = (t + 1) * 64, k2 = (t + 2) * 64, k3 = (t + 3) * 64;

        // phase 1: buf0 (mh0,nh0); stage A-mh1 -> buf1 (tile t+1)
        DS_A(aRd0, 0); DS_B(bRd0, 0, bF0);
        if (t + 1 < NT) STAGE_A(1, 1, k1);
        CFENCE; BARRIER; CFENCE;
        MFMA_Q(0, 0, bF0);
        CFENCE; BARRIER; CFENCE;

        // phase 2: buf0 (mh0,nh1); stage A-mh0 -> buf0 (tile t+2)
        DS_B(bRd0, 1, bF1);
        if (t + 2 < NT) STAGE_A(0, 0, k2);
        CFENCE; BARRIER; CFENCE;
        MFMA_Q(0, 1, bF1);
        CFENCE; BARRIER; CFENCE;

        // phase 3: buf0 (mh1,nh0); stage B-nh0 -> buf0 (tile t+2)
        DS_A(aRd0, 1);
        if (t + 2 < NT) STAGE_B(0, 0, k2);
        CFENCE; BARRIER; CFENCE;
        MFMA_Q(1, 0, bF0);
        CFENCE; BARRIER; CFENCE;

        // phase 4: buf0 (mh1,nh1); stage B-nh1 -> buf0 (tile t+2); vmcnt
        if (t + 2 < NT) STAGE_B(0, 1, k2);
        if (it + 1 == NITER) asm volatile("s_waitcnt vmcnt(0)" ::: "memory");
        else                 asm volatile("s_waitcnt vmcnt(6)" ::: "memory");
        CFENCE; BARRIER; CFENCE;
        MFMA_Q(1, 1, bF1);
        CFENCE; BARRIER; CFENCE;

        // phase 5: buf1 (mh0,nh0); stage A-mh1 -> buf0 (tile t+2)
        DS_A(aRd1, 0); DS_B(bRd1, 0, bF0);
        if (t + 2 < NT) STAGE_A(0, 1, k2);
        CFENCE; BARRIER; CFENCE;
        MFMA_Q(0, 0, bF0);
        CFENCE; BARRIER; CFENCE;

        // phase 6: buf1 (mh0,nh1); stage A-mh0 -> buf1 (tile t+3)
        DS_B(bRd1, 1, bF1);
        if (t + 3 < NT) STAGE_A(1, 0, k3);
        CFENCE; BARRIER; CFENCE;
        MFMA_Q(0, 1, bF1);
        CFENCE; BARRIER; CFENCE;

        // phase 7: buf1 (mh1,nh0); stage B-nh0 -> buf1 (tile t+3)
        DS_A(aRd1, 1);
        if (t + 3 < NT) STAGE_B(1, 0, k3);
        CFENCE; BARRIER; CFENCE;
        MFMA_Q(1, 0, bF0);
        CFENCE; BARRIER; CFENCE;

        // phase 8: buf1 (mh1,nh1); stage B-nh1 -> buf1 (tile t+3); vmcnt
        if (t + 3 < NT) STAGE_B(1, 1, k3);
        if (it + 1 < NITER) asm volatile("s_waitcnt vmcnt(6)" ::: "memory");
        CFENCE; BARRIER; CFENCE;
        MFMA_Q(1, 1, bF1);
        CFENCE; BARRIER; CFENCE;
    }

#undef STAGE_A
#undef STAGE_B
#undef DS_A
#undef DS_B
#undef MFMA_Q

    // ---- epilogue: C/D layout col=lane&15, row=quad*4+reg ----
    const long long crow0 = (long long)bm * 256 + wm * 128 + fq * 4;
    const int ccol0 = bn * 256 + wn * 64 + fr;
#pragma unroll
    for (int i = 0; i < 8; i++) {
#pragma unroll
        for (int r = 0; r < 4; r++) {
            const long long row = crow0 + i * 16 + r;
            const float bvr = (bias_mode == 2) ? bf2f(bias[row]) : 0.0f;
#pragma unroll
            for (int j = 0; j < 4; j++) {
                const int col = ccol0 + j * 16;
                const float bv = (bias_mode == 1) ? bf2f(bias[col]) : bvr;
                C[row * ldc + col] = f2bf(acc[i][j][r] * scale + bv);
            }
        }
    }
}

// ---------------------------------------------------------------------------
// In-place row softmax over 1024 bf16 elements. One wave per row.
// ---------------------------------------------------------------------------
__global__ __launch_bounds__(256) void softmax_kernel(u16* __restrict__ S)
{
    const int tid = threadIdx.x, lane = tid & 63, wave = tid >> 6;
    const long long row = (long long)blockIdx.x * 4 + wave;
    u16* p = S + row * 1024 + lane * 16;
    union { uint4 q[2]; u16 u[16]; } d;
    d.q[0] = *(const uint4*)p;
    d.q[1] = *(const uint4*)(p + 8);
    float x[16];
    float mx = -1e30f;
#pragma unroll
    for (int j = 0; j < 16; j++) { x[j] = bf2f(d.u[j]); mx = fmaxf(mx, x[j]); }
#pragma unroll
    for (int m = 1; m < 64; m <<= 1) mx = fmaxf(mx, __shfl_xor(mx, m));
    float s = 0.f;
#pragma unroll
    for (int j = 0; j < 16; j++) { x[j] = __expf(x[j] - mx); s += x[j]; }
#pragma unroll
    for (int m = 1; m < 64; m <<= 1) s += __shfl_xor(s, m);
    const float inv = 1.0f / s;
#pragma unroll
    for (int j = 0; j < 16; j++) d.u[j] = f2bf(x[j] * inv);
    *(uint4*)p = d.q[0];
    *(uint4*)(p + 8) = d.q[1];
}

// ---------------------------------------------------------------------------
// LayerNorm(obj + I) * g + b -> out. One block per row (objMask variant).
// ---------------------------------------------------------------------------
__global__ __launch_bounds__(256) void ln_kernel(
    const u16* __restrict__ obj, const u16* __restrict__ gam,
    const u16* __restrict__ bet, const u16* __restrict__ I,
    void* __restrict__ outv, long long outOff, int objMask,
    const int* __restrict__ flag)
{
    __shared__ float red[8];
    const int tid = threadIdx.x, lane = tid & 63, wave = tid >> 6;
    const long long base = (long long)blockIdx.x * 1024;
    const long long obase = (long long)(blockIdx.x & objMask) * 1024;
    const int c = tid * 4;
    union { uint2 q; u16 u[4]; } ov, iv, gv, bv;
    ov.q = *(const uint2*)(obj + obase + c);
    iv.q = *(const uint2*)(I + base + c);
    float x[4], s = 0.f, sq = 0.f;
#pragma unroll
    for (int j = 0; j < 4; j++) {
        x[j] = bf2f(ov.u[j]) + bf2f(iv.u[j]);
        s += x[j]; sq += x[j] * x[j];
    }
#pragma unroll
    for (int m = 1; m < 64; m <<= 1) {
        s += __shfl_xor(s, m);
        sq += __shfl_xor(sq, m);
    }
    if (lane == 0) { red[wave] = s; red[4 + wave] = sq; }
    __syncthreads();
    s = red[0] + red[1] + red[2] + red[3];
    sq = red[4] + red[5] + red[6] + red[7];
    const float mu = s * (1.0f / 1024.0f);
    const float var = fmaxf(sq * (1.0f / 1024.0f) - mu * mu, 0.0f);
    const float rs = rsqrtf(var + 1e-5f);
    gv.q = *(const uint2*)(gam + c);
    bv.q = *(const uint2*)(bet + c);
    float y[4];
#pragma unroll
    for (int j = 0; j < 4; j++)
        y[j] = (x[j] - mu) * rs * bf2f(gv.u[j]) + bf2f(bv.u[j]);
    if (flag[0]) {
        float4 w; w.x = y[0]; w.y = y[1]; w.z = y[2]; w.w = y[3];
        *(float4*)((float*)outv + outOff + base + c) = w;
    } else {
        union { uint2 q; u16 u[4]; } wv;
#pragma unroll
        for (int j = 0; j < 4; j++) wv.u[j] = f2bf(y[j]);
        *(uint2*)((u16*)outv + outOff + base + c) = wv.q;
    }
}

// ---------------------------------------------------------------------------
// Merged LayerNorm, BOTH sides per row: reads obj once, I1 and I2 = I+iOff,
// writes out row and out row+oOff. One block per row (16384 blocks).
// ---------------------------------------------------------------------------
__global__ __launch_bounds__(256) void ln2_kernel(
    const u16* __restrict__ obj, const u16* __restrict__ gam,
    const u16* __restrict__ bet, const u16* __restrict__ I, long long iOff,
    void* __restrict__ outv, long long oOff, const int* __restrict__ flag)
{
    __shared__ float red[16];
    const int tid = threadIdx.x, lane = tid & 63, wave = tid >> 6;
    const long long base = (long long)blockIdx.x * 1024;
    const int c = tid * 4;
    union { uint2 q; u16 u[4]; } ov, i1, i2, gv, bv;
    ov.q = *(const uint2*)(obj + base + c);
    i1.q = *(const uint2*)(I + base + c);
    i2.q = *(const uint2*)(I + iOff + base + c);
    float x1[4], x2[4], s1 = 0.f, q1 = 0.f, s2 = 0.f, q2 = 0.f;
#pragma unroll
    for (int j = 0; j < 4; j++) {
        const float o = bf2f(ov.u[j]);
        x1[j] = o + bf2f(i1.u[j]);
        x2[j] = o + bf2f(i2.u[j]);
        s1 += x1[j]; q1 += x1[j] * x1[j];
        s2 += x2[j]; q2 += x2[j] * x2[j];
    }
#pragma unroll
    for (int m = 1; m < 64; m <<= 1) {
        s1 += __shfl_xor(s1, m); q1 += __shfl_xor(q1, m);
        s2 += __shfl_xor(s2, m); q2 += __shfl_xor(q2, m);
    }
    if (lane == 0) {
        red[wave] = s1; red[4 + wave] = q1;
        red[8 + wave] = s2; red[12 + wave] = q2;
    }
    __syncthreads();
    s1 = red[0] + red[1] + red[2] + red[3];
    q1 = red[4] + red[5] + red[6] + red[7];
    s2 = red[8] + red[9] + red[10] + red[11];
    q2 = red[12] + red[13] + red[14] + red[15];
    const float mu1 = s1 * (1.0f / 1024.0f);
    const float rs1 = rsqrtf(fmaxf(q1 * (1.0f / 1024.0f) - mu1 * mu1, 0.0f)
                             + 1e-5f);
    const float mu2 = s2 * (1.0f / 1024.0f);
    const float rs2 = rsqrtf(fmaxf(q2 * (1.0f / 1024.0f) - mu2 * mu2, 0.0f)
                             + 1e-5f);
    gv.q = *(const uint2*)(gam + c);
    bv.q = *(const uint2*)(bet + c);
    float y1[4], y2[4];
#pragma unroll
    for (int j = 0; j < 4; j++) {
        const float g = bf2f(gv.u[j]), b = bf2f(bv.u[j]);
        y1[j] = (x1[j] - mu1) * rs1 * g + b;
        y2[j] = (x2[j] - mu2) * rs2 * g + b;
    }
    if (flag[0]) {
        float4 w1, w2;
        w1.x = y1[0]; w1.y = y1[1]; w1.z = y1[2]; w1.w = y1[3];
        w2.x = y2[0]; w2.y = y2[1]; w2.z = y2[2]; w2.w = y2[3];
        *(float4*)((float*)outv + base + c) = w1;
        *(float4*)((float*)outv + oOff + base + c) = w2;
    } else {
        union { uint2 q; u16 u[4]; } w1, w2;
#pragma unroll
        for (int j = 0; j < 4; j++) { w1.u[j] = f2bf(y1[j]); w2.u[j] = f2bf(y2[j]); }
        *(uint2*)((u16*)outv + base + c) = w1.q;
        *(uint2*)((u16*)outv + oOff + base + c) = w2.q;
    }
}

// ---------------------------------------------------------------------------
extern "C" void kernel_launch(void* const* d_in, const int* in_sizes, int n_in,
                              void* d_out, int out_size, void* d_ws, size_t ws_size,
                              hipStream_t stream)
{
    u16* ws = (u16*)d_ws;
    int* flag = (int*)d_ws;              // header: first 64 bytes
    const dim3 blk(256);
    const dim3 blk5(512);
    const float scale = 0.03125f;        // 1024^-0.5
    const long long Eobj = 16777216;     // 8*2048*1024
    const long long Ekv  = 8388608;      // 8*1024*1024
    const long long sQ = 2048LL * 1024, sK = 1024LL * 1024;
    const int ALLZ = 255;                // zAmask: full z indexing
    const int NOZ = -1;                  // zShift: use blockIdx.z

    detect_kernel<<<dim3(1), blk, 0, stream>>>((const u16*)d_in[0], flag);

    // merged conversion into contiguous region after 64B header
    const size_t wsElems = ws_size / 2;
    ConvArgs ca;
    long long cur = 32;
    u16* cIn[15];
    for (int i = 0; i < 15; i++) {
        ca.src[i] = d_in[i];
        ca.off[i] = cur - 32;
        cIn[i] = ws + cur;
        cur += in_sizes[i];
    }
    ca.off[15] = cur - 32;
    const long long convTotal = cur - 32;
    const bool canConv = wsElems >= (size_t)(32 + convTotal + 8388608 + 32);
    if (canConv) {
        const int grid = (int)((convTotal / 8 + 255) / 256);
        convert_all_kernel<<<dim3(grid), blk, 0, stream>>>(ca, ws + 32, flag);
    } else {
        for (int i = 0; i < 15; i++) cIn[i] = (u16*)d_in[i];
        cur = 32;
    }
    const u16* obj = cIn[0];  const u16* sub = cIn[1];  const u16* scene = cIn[2];
    const u16* W_q = cIn[3];  const u16* b_q = cIn[4];
    const u16* W_sk = cIn[5]; const u16* b_sk = cIn[6];
    const u16* W_sv = cIn[7]; const u16* b_sv = cIn[8];
    const u16* W_ek = cIn[9]; const u16* b_ek = cIn[10];
    const u16* W_ev = cIn[11]; const u16* b_ev = cIn[12];
    const u16* ln_g = cIn[13]; const u16* ln_b = cIn[14];

    // planMerged: both attention sides in single dispatches (S,O doubled)
    const bool planMerged = canConv &&
        wsElems >= (size_t)(cur + 5 * Eobj + 4 * Ekv);
    const bool planComb = canConv &&
        wsElems >= (size_t)(cur + 3 * Eobj + 4 * Ekv);
    const bool planA = wsElems >= (size_t)(cur + 3 * Eobj + 2 * Ekv);

    if (planMerged) {
        u16* Q  = ws + cur;          // Eobj      (contiguous with Kb below)
        u16* Kb = Q + Eobj;          // 2*Ekv : [a][z][1024][1024]
        u16* VT = Kb + 2 * Ekv;      // 2*Ekv : VT[p][a*8192 + z*1024 + s]
        u16* S  = VT + 2 * Ekv;      // 2*Eobj: [a][z][2048][1024]
        u16* O  = S + 2 * Eobj;      // 2*Eobj

        // Merged Q+K projection: A = [obj;sub;scene] (contiguous, 32768 rows),
        // C = [Q;Kb] (contiguous), 3-way W select by bm (64/96 of nbm=128).
        gemm256_kernel<<<dim3(512, 1, 1), blk5, 0, stream>>>(
            obj, W_q, Q, b_q, W_sk, b_sk, W_ek, b_ek,
            1.0f, 1, 3, 2, ALLZ, NOZ, 1024, 1024, 1024, 1024, 0, 0, 0);
        // VT[p][n] = {W_sv|W_ev}[p,:] . [sub;scene][n,:] + bias (dual bn)
        gemm256_kernel<<<dim3(256, 1, 1), blk5, 0, stream>>>(
            W_sv, sub, VT, b_sv, W_ev, b_ev, nullptr, nullptr,
            1.0f, 2, 2, 6, ALLZ, NOZ, 1024, 1024, 16384, 1024, 0, 0, 0);

        // S[a][z] = Q[z] . Kb[a][z]^T : flattened z'=id>>5, A indexed z'&7
        gemm256_kernel<<<dim3(512, 1, 1), blk5, 0, stream>>>(
            Q, Kb, S, nullptr, nullptr, nullptr, nullptr, nullptr,
            scale, 0, 0, 2, 7, 5, 1024, 1024, 1024, 1024, sQ, sK, sQ);
        softmax_kernel<<<dim3(8192), blk, 0, stream>>>(S);
        // O[a][z] = S[a][z] . V; VT col offset z'*1024
        gemm256_kernel<<<dim3(512, 1, 1), blk5, 0, stream>>>(
            S, VT, O, nullptr, nullptr, nullptr, nullptr, nullptr,
            1.0f, 0, 0, 2, ALLZ, 5, 1024, 16384, 1024, 1024, sQ, 1024, sQ);
        // Merged LN: both sides per row, obj read once
        ln2_kernel<<<dim3(16384), blk, 0, stream>>>(
            obj, ln_g, ln_b, O, Eobj, d_out, Eobj, flag);
    } else if (planComb) {
        u16* Q  = ws + cur;          // Eobj
        u16* Kb = Q + Eobj;          // 2*Ekv
        u16* VT = Kb + 2 * Ekv;      // 2*Ekv
        u16* S  = VT + 2 * Ekv;      // Eobj
        u16* O  = S + Eobj;          // Eobj

        gemm256_kernel<<<dim3(512, 1, 1), blk5, 0, stream>>>(
            obj, W_q, Q, b_q, W_sk, b_sk, W_ek, b_ek,
            1.0f, 1, 3, 2, ALLZ, NOZ, 1024, 1024, 1024, 1024, 0, 0, 0);
        gemm256_kernel<<<dim3(256, 1, 1), blk5, 0, stream>>>(
            W_sv, sub, VT, b_sv, W_ev, b_ev, nullptr, nullptr,
            1.0f, 2, 2, 6, ALLZ, NOZ, 1024, 1024, 16384, 1024, 0, 0, 0);

        for (int a = 0; a < 2; a++) {
            gemm256_kernel<<<dim3(32, 1, 8), blk5, 0, stream>>>(
                Q, Kb + (long long)a * Ekv, S, nullptr, nullptr, nullptr,
                nullptr, nullptr,
                scale, 0, 0, 2, ALLZ, NOZ, 1024, 1024, 1024, 1024, sQ, sK, sQ);
            softmax_kernel<<<dim3(4096), blk, 0, stream>>>(S);
            gemm256_kernel<<<dim3(32, 1, 8), blk5, 0, stream>>>(
                S, VT + a * 8192, O, nullptr, nullptr, nullptr, nullptr, nullptr,
                1.0f, 0, 0, 2, ALLZ, NOZ, 1024, 16384, 1024, 1024, sQ, 1024, sQ);
            ln_kernel<<<dim3(16384), blk, 0, stream>>>(
                obj, ln_g, ln_b, O, d_out, (long long)a * Eobj, 0x7fffffff,
                flag);
        }
    } else if (planA) {
        u16* Q  = ws + cur;
        u16* Kb = Q + Eobj;
        u16* VT = Kb + Ekv;
        u16* S  = VT + Ekv;
        u16* O  = S + Eobj;

        gemm256_kernel<<<dim3(256, 1, 1), blk5, 0, stream>>>(
            obj, W_q, Q, b_q, nullptr, nullptr, nullptr, nullptr,
            1.0f, 1, 0, 2, ALLZ, NOZ, 1024, 1024, 1024, 1024, 0, 0, 0);

        for (int a = 0; a < 2; a++) {
            const u16* X  = a ? scene : sub;
            const u16* Wk = a ? W_ek : W_sk;
            const u16* bk = a ? b_ek : b_sk;
            const u16* Wv = a ? W_ev : W_sv;
            const u16* bv = a ? b_ev : b_sv;

            gemm256_kernel<<<dim3(128, 1, 1), blk5, 0, stream>>>(
                X, Wk, Kb, bk, nullptr, nullptr, nullptr, nullptr,
                1.0f, 1, 0, 2, ALLZ, NOZ, 1024, 1024, 1024, 1024, 0, 0, 0);
            gemm256_kernel<<<dim3(128, 1, 1), blk5, 0, stream>>>(
                Wv, X, VT, bv, nullptr, nullptr, nullptr, nullptr,
                1.0f, 2, 0, 5, ALLZ, NOZ, 1024, 1024, 8192, 1024, 0, 0, 0);
            gemm256_kernel<<<dim3(32, 1, 8), blk5, 0, stream>>>(
                Q, Kb, S, nullptr, nullptr, nullptr, nullptr, nullptr,
                scale, 0, 0, 2, ALLZ, NOZ, 1024, 1024, 1024, 1024, sQ, sK, sQ);
            softmax_kernel<<<dim3(4096), blk, 0, stream>>>(S);
            gemm256_kernel<<<dim3(32, 1, 8), blk5, 0, stream>>>(
                S, VT, O, nullptr, nullptr, nullptr, nullptr, nullptr,
                1.0f, 0, 0, 2, ALLZ, NOZ, 1024, 8192, 1024, 1024, sQ, 1024, sQ);
            ln_kernel<<<dim3(16384), blk, 0, stream>>>(
                obj, ln_g, ln_b, O, d_out, (long long)a * Eobj, 0x7fffffff,
                flag);
        }
    } else {
        // per-batch fallback: 8.39M elems of pipeline scratch
        u16* Qb = ws + cur;              // 2M
        u16* Kb = Qb + 2097152;          // 1M
        u16* VT = Kb + 1048576;          // 1M
        u16* S  = VT + 1048576;          // 2M
        u16* O  = S + 2097152;           // 2M

        for (int a = 0; a < 2; a++) {
            const u16* X  = a ? scene : sub;
            const u16* Wk = a ? W_ek : W_sk;
            const u16* bk = a ? b_ek : b_sk;
            const u16* Wv = a ? W_ev : W_sv;
            const u16* bv = a ? b_ev : b_sv;

            for (int z = 0; z < 8; z++) {
                const u16* objz = obj + (long long)z * sQ;
                const u16* Xz   = X + (long long)z * sK;
                gemm256_kernel<<<dim3(32, 1, 1), blk5, 0, stream>>>(
                    objz, W_q, Qb, b_q, nullptr, nullptr, nullptr, nullptr,
                    1.0f, 1, 0, 2, ALLZ, NOZ, 1024, 1024, 1024, 1024, 0, 0, 0);
                gemm256_kernel<<<dim3(16, 1, 1), blk5, 0, stream>>>(
                    Xz, Wk, Kb, bk, nullptr, nullptr, nullptr, nullptr,
                    1.0f, 1, 0, 2, ALLZ, NOZ, 1024, 1024, 1024, 1024, 0, 0, 0);
                gemm256_kernel<<<dim3(16, 1, 1), blk5, 0, stream>>>(
                    Wv, Xz, VT, bv, nullptr, nullptr, nullptr, nullptr,
                    1.0f, 2, 0, 2, ALLZ, NOZ, 1024, 1024, 1024, 1024, 0, 0, 0);
                gemm256_kernel<<<dim3(32, 1, 1), blk5, 0, stream>>>(
                    Qb, Kb, S, nullptr, nullptr, nullptr, nullptr, nullptr,
                    scale, 0, 0, 2, ALLZ, NOZ, 1024, 1024, 1024, 1024, 0, 0, 0);
                softmax_kernel<<<dim3(512), blk, 0, stream>>>(S);
                gemm256_kernel<<<dim3(32, 1, 1), blk5, 0, stream>>>(
                    S, VT, O, nullptr, nullptr, nullptr, nullptr, nullptr,
                    1.0f, 0, 0, 2, ALLZ, NOZ, 1024, 1024, 1024, 1024, 0, 0, 0);
                ln_kernel<<<dim3(2048), blk, 0, stream>>>(
                    objz, ln_g, ln_b, O, d_out,
                    (long long)a * Eobj + (long long)z * sQ, 0x7fffffff,
                    flag);
            }
        }
    }

    (void)n_in; (void)out_size;
}

// Round 12
// 580.255 us; speedup vs baseline: 1.0568x; 1.0568x over previous
//
#include <hip/hip_runtime.h>

typedef unsigned short u16;
typedef short bf16x8 __attribute__((ext_vector_type(8)));
typedef float f32x4 __attribute__((ext_vector_type(4)));

__device__ __forceinline__ float bf2f(u16 s) {
    union { unsigned u; float f; } v;
    v.u = ((unsigned)s) << 16;
    return v.f;
}
__device__ __forceinline__ u16 f2bf(float f) {
    union { float f; unsigned u; } v;
    v.f = f;
    unsigned r = v.u + 0x7fffu + ((v.u >> 16) & 1u);  // RNE
    return (u16)(r >> 16);
}

#define GLD16(gp, lp)                                                  \
    __builtin_amdgcn_global_load_lds(                                  \
        (__attribute__((address_space(1))) void*)(gp),                 \
        (__attribute__((address_space(3))) void*)(lp), 16, 0, 0)

#define CFENCE asm volatile("" ::: "memory")
#define BARRIER __builtin_amdgcn_s_barrier()

// ---------------------------------------------------------------------------
// Detect whether d_in[0] is f32 (flag=1) or bf16 (flag=0).
// ---------------------------------------------------------------------------
__global__ __launch_bounds__(256) void detect_kernel(
    const u16* __restrict__ src, int* __restrict__ flag)
{
    __shared__ int red[4];
    const int tid = threadIdx.x;
    int cnt = 0;
    for (int j = 0; j < 64; j++) {
        const u16 v = src[tid * 64 + j];
        const int e = (v >> 7) & 0xFF;
        cnt += (e >= 0x90) ? 1 : 0;
    }
#pragma unroll
    for (int m = 1; m < 64; m <<= 1) cnt += __shfl_xor(cnt, m);
    if ((tid & 63) == 0) red[tid >> 6] = cnt;
    __syncthreads();
    if (tid == 0) {
        const int total = red[0] + red[1] + red[2] + red[3];
        flag[0] = (total > 1024) ? 1 : 0;
    }
}

// ---------------------------------------------------------------------------
// Single merged conversion: all 15 inputs -> contiguous bf16 region in ws.
// ---------------------------------------------------------------------------
struct ConvArgs {
    const void* src[15];
    long long   off[16];   // cumulative element offsets in dst (off[15]=total)
};

__global__ __launch_bounds__(256) void convert_all_kernel(
    ConvArgs a, u16* __restrict__ dst, const int* __restrict__ flag)
{
    const long long i = ((long long)blockIdx.x * 256 + threadIdx.x) * 8;
    if (i >= a.off[15]) return;
    int s = 0;
#pragma unroll
    for (int t = 1; t < 15; t++) s += (i >= a.off[t]) ? 1 : 0;
    const long long local = i - a.off[s];
    union { uint4 q; u16 u[8]; } o;
    if (flag[0]) {
        const float* sp = (const float*)a.src[s] + local;
        const float4 x = *(const float4*)sp;
        const float4 y = *(const float4*)(sp + 4);
        o.u[0] = f2bf(x.x); o.u[1] = f2bf(x.y);
        o.u[2] = f2bf(x.z); o.u[3] = f2bf(x.w);
        o.u[4] = f2bf(y.x); o.u[5] = f2bf(y.y);
        o.u[6] = f2bf(y.z); o.u[7] = f2bf(y.w);
    } else {
        o.q = *(const uint4*)((const u16*)a.src[s] + local);
    }
    *(uint4*)(dst + i) = o.q;
}

// ---------------------------------------------------------------------------
// 256x256-tile GEMM, 8-phase pipelined schedule (T1+T2+T3+T4+T5).
// *** BYTE-EXACT restore of the round-4 kernel that measured QK/PV=80us,
// *** MfmaUtil 34%. Round 9's added dualMode=3 params/branch in THIS kernel
// *** coincided with QK/PV 80->103-108us at identical call args (codegen
// *** perturbation suspect); the 3-way variant now lives in a separate
// *** kernel below, used only for the merged Q+K projection.
//   C[M,N](bf16) = scale * (A[M,K] . B[N,K]^T) + bias
// 512 threads = 8 waves (2 M x 4 N), per-wave 128x64 via 8x4 MFMA 16x16x32.
// BK=64, LDS = 2 buffers x (A 32KB + B 32KB) = 128KB -> 1 block/CU.
// Staging: global_load_lds w=16, linear LDS dest, XOR col-block swizzle on
//   the GLOBAL source address -> conflict-free ds_read_b128 (measured 0).
// Schedule per iteration (2 K-tiles): 8 phases; counted vmcnt(6) at
//   phases 4 & 8 only; no explicit lgkmcnt (compiler places them better).
// dualMode: 1 = {B,bias}->alt when bm>=nbm/2; 2 = {A,bias}->alt bn>=nbn/2.
// bias_mode: 0 none, 1 bias[col], 2 bias[row].
// Batching: zShift>=0 -> z = swizzled_id >> zShift; else z = blockIdx.z.
//   A += (z & zAmask)*sA, B += z*sB, C += z*sC.
// ---------------------------------------------------------------------------
__global__ __launch_bounds__(512, 2) void gemm256_kernel(
    const u16* __restrict__ A, const u16* __restrict__ B,
    u16* __restrict__ C, const u16* __restrict__ bias,
    const u16* __restrict__ alt, const u16* __restrict__ biasAlt,
    float scale, int bias_mode, int dualMode, int nbnShift, int zAmask,
    int zShift,
    int lda, int ldb, int ldc, int K,
    long long sA, long long sB, long long sC)
{
    __shared__ alignas(16) u16 lds[4][256 * 64];  // [buf*2 + op], 128 KB

    const int tid  = threadIdx.x;
    const int lane = tid & 63;
    const int wave = tid >> 6;
    const int wm   = wave >> 2;      // 0..1
    const int wn   = wave & 3;       // 0..3

    // T1: bijective XCD swizzle (m204) over the full flattened grid
    const int nwg = gridDim.x;
    int id = blockIdx.x;
    if (nwg >= 8) {
        const int q = nwg >> 3, r = nwg & 7;
        const int x = id & 7, sidx = id >> 3;
        id = (x < r ? x * (q + 1) : r * (q + 1) + (x - r) * q) + sidx;
    }
    int z, rem;
    if (zShift >= 0) { z = id >> zShift; rem = id & ((1 << zShift) - 1); }
    else             { z = blockIdx.z;   rem = id; }
    const int nbn = 1 << nbnShift;
    const int bm = rem >> nbnShift, bn = rem & (nbn - 1);
    const int nbm = ((zShift >= 0) ? (1 << zShift) : nwg) >> nbnShift;

    if (dualMode == 1 && bm >= (nbm >> 1)) { B = alt; bias = biasAlt; }
    if (dualMode == 2 && bn >= (nbn >> 1)) { A = alt; bias = biasAlt; }

    A += (long long)(z & zAmask) * sA;
    B += (long long)z * sB;
    C += (long long)z * sC;

    // ---- staging addresses (per-lane global, wave-uniform LDS base) ----
    const int rw  = lane >> 3;           // 0..7 row within wave chunk
    const int cb  = lane & 7;            // LDS col-block
    const int scb = cb ^ rw;             // swizzled GLOBAL col-block
    const int srow = wave * 8 + rw;      // 0..63
    const int bRowBase = ((wave & 4) << 4) + ((wave & 3) << 3);

    const u16* aG = A + (long long)(bm * 256 + srow) * lda + scb * 8;
    const u16* bG = B + (long long)(bn * 256 + bRowBase + rw) * ldb + scb * 8;
    const long long a64  = (long long)64 * lda;
    const long long a128 = (long long)128 * lda;
    const long long b32  = (long long)32 * ldb;
    const long long b128 = (long long)128 * ldb;

#define STAGE_A(buf, mh, k0) do {                                         \
        u16* d_ = &lds[(buf) * 2][((mh) * 64 + wave * 8) * 64];           \
        GLD16(aG + (k0) + ((mh) ? a64 : 0), d_);                          \
        GLD16(aG + (k0) + ((mh) ? a64 : 0) + a128, d_ + 128 * 64);        \
    } while (0)
#define STAGE_B(buf, nh, k0) do {                                         \
        u16* d_ = &lds[(buf) * 2 + 1][(bRowBase + (nh) * 32) * 64];       \
        GLD16(bG + (k0) + ((nh) ? b32 : 0), d_);                          \
        GLD16(bG + (k0) + ((nh) ? b32 : 0) + b128, d_ + 128 * 64);        \
    } while (0)

    // ---- fragment read addressing (XOR-unswizzle on read) ----
    const int fr = lane & 15, fq = lane >> 4;
    const int c0 = ((fq ^ (fr & 7)) << 3);
    const int c1 = (((4 | fq) ^ (fr & 7)) << 3);
    const u16* aRd0 = &lds[0][(wm * 128 + fr) * 64];
    const u16* aRd1 = &lds[2][(wm * 128 + fr) * 64];
    const u16* bRd0 = &lds[1][(wn * 64 + fr) * 64];
    const u16* bRd1 = &lds[3][(wn * 64 + fr) * 64];

    bf16x8 aF[4][2], bF0[2][2], bF1[2][2];
    f32x4 acc[8][4];
#pragma unroll
    for (int i = 0; i < 8; i++)
#pragma unroll
        for (int j = 0; j < 4; j++) {
            acc[i][j][0] = 0.f; acc[i][j][1] = 0.f;
            acc[i][j][2] = 0.f; acc[i][j][3] = 0.f;
        }

#define DS_A(base, mh) do {                                               \
        _Pragma("unroll") for (int i_ = 0; i_ < 4; i_++) {                \
            const u16* p_ = (base) + ((mh) * 64 + i_ * 16) * 64;          \
            aF[i_][0] = *(const bf16x8*)(p_ + c0);                        \
            aF[i_][1] = *(const bf16x8*)(p_ + c1);                        \
        } } while (0)
#define DS_B(base, nh, arr) do {                                          \
        _Pragma("unroll") for (int j_ = 0; j_ < 2; j_++) {                \
            const u16* p_ = (base) + ((nh) * 32 + j_ * 16) * 64;          \
            arr[j_][0] = *(const bf16x8*)(p_ + c0);                       \
            arr[j_][1] = *(const bf16x8*)(p_ + c1);                       \
        } } while (0)
#define MFMA_Q(mh, nh, arr) do {                                          \
        __builtin_amdgcn_s_setprio(1);                                    \
        _Pragma("unroll") for (int i_ = 0; i_ < 4; i_++)                  \
        _Pragma("unroll") for (int j_ = 0; j_ < 2; j_++) {                \
            f32x4 v_ = acc[(mh) * 4 + i_][(nh) * 2 + j_];                 \
            v_ = __builtin_amdgcn_mfma_f32_16x16x32_bf16(                 \
                     aF[i_][0], arr[j_][0], v_, 0, 0, 0);                 \
            v_ = __builtin_amdgcn_mfma_f32_16x16x32_bf16(                 \
                     aF[i_][1], arr[j_][1], v_, 0, 0, 0);                 \
            acc[(mh) * 4 + i_][(nh) * 2 + j_] = v_;                       \
        }                                                                 \
        __builtin_amdgcn_s_setprio(0);                                    \
    } while (0)

    const int NT = K >> 6;        // K / 64, assumed even and >= 2
    const int NITER = NT >> 1;

    // ---- prologue: tile0 full -> buf0; tile1 {A-mh0, B-nh0, B-nh1} -> buf1
    STAGE_A(0, 0, 0); STAGE_A(0, 1, 0); STAGE_B(0, 0, 0); STAGE_B(0, 1, 0);
    if (NT > 1) {
        STAGE_A(1, 0, 64); STAGE_B(1, 0, 64); STAGE_B(1, 1, 64);
        asm volatile("s_waitcnt vmcnt(6)" ::: "memory");
    } else {
        asm volatile("s_waitcnt vmcnt(0)" ::: "memory");
    }
    CFENCE; BARRIER; CFENCE;

    for (int it = 0; it < NITER; it++) {
        const int t = it * 2;
        const int k1 = (t + 1) * 64, k2 = (t + 2) * 64, k3 = (t + 3) * 64;

        // phase 1: buf0 (mh0,nh0); stage A-mh1 -> buf1 (tile t+1)
        DS_A(aRd0, 0); DS_B(bRd0, 0, bF0);
        if (t + 1 < NT) STAGE_A(1, 1, k1);
        CFENCE; BARRIER; CFENCE;
        MFMA_Q(0, 0, bF0);
        CFENCE; BARRIER; CFENCE;

        // phase 2: buf0 (mh0,nh1); stage A-mh0 -> buf0 (tile t+2)
        DS_B(bRd0, 1, bF1);
        if (t + 2 < NT) STAGE_A(0, 0, k2);
        CFENCE; BARRIER; CFENCE;
        MFMA_Q(0, 1, bF1);
        CFENCE; BARRIER; CFENCE;

        // phase 3: buf0 (mh1,nh0); stage B-nh0 -> buf0 (tile t+2)
        DS_A(aRd0, 1);
        if (t + 2 < NT) STAGE_B(0, 0, k2);
        CFENCE; BARRIER; CFENCE;
        MFMA_Q(1, 0, bF0);
        CFENCE; BARRIER; CFENCE;

        // phase 4: buf0 (mh1,nh1); stage B-nh1 -> buf0 (tile t+2); vmcnt
        if (t + 2 < NT) STAGE_B(0, 1, k2);
        if (it + 1 == NITER) asm volatile("s_waitcnt vmcnt(0)" ::: "memory");
        else                 asm volatile("s_waitcnt vmcnt(6)" ::: "memory");
        CFENCE; BARRIER; CFENCE;
        MFMA_Q(1, 1, bF1);
        CFENCE; BARRIER; CFENCE;

        // phase 5: buf1 (mh0,nh0); stage A-mh1 -> buf0 (tile t+2)
        DS_A(aRd1, 0); DS_B(bRd1, 0, bF0);
        if (t + 2 < NT) STAGE_A(0, 1, k2);
        CFENCE; BARRIER; CFENCE;
        MFMA_Q(0, 0, bF0);
        CFENCE; BARRIER; CFENCE;

        // phase 6: buf1 (mh0,nh1); stage A-mh0 -> buf1 (tile t+3)
        DS_B(bRd1, 1, bF1);
        if (t + 3 < NT) STAGE_A(1, 0, k3);
        CFENCE; BARRIER; CFENCE;
        MFMA_Q(0, 1, bF1);
        CFENCE; BARRIER; CFENCE;

        // phase 7: buf1 (mh1,nh0); stage B-nh0 -> buf1 (tile t+3)
        DS_A(aRd1, 1);
        if (t + 3 < NT) STAGE_B(1, 0, k3);
        CFENCE; BARRIER; CFENCE;
        MFMA_Q(1, 0, bF0);
        CFENCE; BARRIER; CFENCE;

        // phase 8: buf1 (mh1,nh1); stage B-nh1 -> buf1 (tile t+3); vmcnt
        if (t + 3 < NT) STAGE_B(1, 1, k3);
        if (it + 1 < NITER) asm volatile("s_waitcnt vmcnt(6)" ::: "memory");
        CFENCE; BARRIER; CFENCE;
        MFMA_Q(1, 1, bF1);
        CFENCE; BARRIER; CFENCE;
    }

#undef STAGE_A
#undef STAGE_B
#undef DS_A
#undef DS_B
#undef MFMA_Q

    // ---- epilogue: C/D layout col=lane&15, row=quad*4+reg ----
    const long long crow0 = (long long)bm * 256 + wm * 128 + fq * 4;
    const int ccol0 = bn * 256 + wn * 64 + fr;
#pragma unroll
    for (int i = 0; i < 8; i++) {
#pragma unroll
        for (int r = 0; r < 4; r++) {
            const long long row = crow0 + i * 16 + r;
            const float bvr = (bias_mode == 2) ? bf2f(bias[row]) : 0.0f;
#pragma unroll
            for (int j = 0; j < 4; j++) {
                const int col = ccol0 + j * 16;
                const float bv = (bias_mode == 1) ? bf2f(bias[col]) : bvr;
                C[row * ldc + col] = f2bf(acc[i][j][r] * scale + bv);
            }
        }
    }
}

// ---------------------------------------------------------------------------
// Same GEMM with 3-way B/bias select by bm (merged Q+K projection ONLY).
// Kept as a SEPARATE kernel so the hot QK^T/PV kernel above compiles
// identically to the round-4 artifact.
// ---------------------------------------------------------------------------
__global__ __launch_bounds__(512, 2) void gemm256p3_kernel(
    const u16* __restrict__ A, const u16* __restrict__ B,
    u16* __restrict__ C, const u16* __restrict__ bias,
    const u16* __restrict__ alt, const u16* __restrict__ biasAlt,
    const u16* __restrict__ alt2, const u16* __restrict__ biasAlt2,
    float scale, int nbnShift,
    int lda, int ldb, int ldc, int K)
{
    __shared__ alignas(16) u16 lds[4][256 * 64];

    const int tid  = threadIdx.x;
    const int lane = tid & 63;
    const int wave = tid >> 6;
    const int wm   = wave >> 2;
    const int wn   = wave & 3;

    const int nwg = gridDim.x;
    int id = blockIdx.x;
    if (nwg >= 8) {
        const int q = nwg >> 3, r = nwg & 7;
        const int x = id & 7, sidx = id >> 3;
        id = (x < r ? x * (q + 1) : r * (q + 1) + (x - r) * q) + sidx;
    }
    const int nbn = 1 << nbnShift;
    const int bm = id >> nbnShift, bn = id & (nbn - 1);
    const int nbm = nwg >> nbnShift;

    if (bm >= 3 * (nbm >> 2))      { B = alt2; bias = biasAlt2; }
    else if (bm >= (nbm >> 1))     { B = alt;  bias = biasAlt; }

    const int rw  = lane >> 3;
    const int cb  = lane & 7;
    const int scb = cb ^ rw;
    const int srow = wave * 8 + rw;
    const int bRowBase = ((wave & 4) << 4) + ((wave & 3) << 3);

    const u16* aG = A + (long long)(bm * 256 + srow) * lda + scb * 8;
    const u16* bG = B + (long long)(bn * 256 + bRowBase + rw) * ldb + scb * 8;
    const long long a64  = (long long)64 * lda;
    const long long a128 = (long long)128 * lda;
    const long long b32  = (long long)32 * ldb;
    const long long b128 = (long long)128 * ldb;

#define STAGE_A(buf, mh, k0) do {                                         \
        u16* d_ = &lds[(buf) * 2][((mh) * 64 + wave * 8) * 64];           \
        GLD16(aG + (k0) + ((mh) ? a64 : 0), d_);                          \
        GLD16(aG + (k0) + ((mh) ? a64 : 0) + a128, d_ + 128 * 64);        \
    } while (0)
#define STAGE_B(buf, nh, k0) do {                                         \
        u16* d_ = &lds[(buf) * 2 + 1][(bRowBase + (nh) * 32) * 64];       \
        GLD16(bG + (k0) + ((nh) ? b32 : 0), d_);                          \
        GLD16(bG + (k0) + ((nh) ? b32 : 0) + b128, d_ + 128 * 64);        \
    } while (0)

    const int fr = lane & 15, fq = lane >> 4;
    const int c0 = ((fq ^ (fr & 7)) << 3);
    const int c1 = (((4 | fq) ^ (fr & 7)) << 3);
    const u16* aRd0 = &lds[0][(wm * 128 + fr) * 64];
    const u16* aRd1 = &lds[2][(wm * 128 + fr) * 64];
    const u16* bRd0 = &lds[1][(wn * 64 + fr) * 64];
    const u16* bRd1 = &lds[3][(wn * 64 + fr) * 64];

    bf16x8 aF[4][2], bF0[2][2], bF1[2][2];
    f32x4 acc[8][4];
#pragma unroll
    for (int i = 0; i < 8; i++)
#pragma unroll
        for (int j = 0; j < 4; j++) {
            acc[i][j][0] = 0.f; acc[i][j][1] = 0.f;
            acc[i][j][2] = 0.f; acc[i][j][3] = 0.f;
        }

#define DS_A(base, mh) do {                                               \
        _Pragma("unroll") for (int i_ = 0; i_ < 4; i_++) {                \
            const u16* p_ = (base) + ((mh) * 64 + i_ * 16) * 64;          \
            aF[i_][0] = *(const bf16x8*)(p_ + c0);                        \
            aF[i_][1] = *(const bf16x8*)(p_ + c1);                        \
        } } while (0)
#define DS_B(base, nh, arr) do {                                          \
        _Pragma("unroll") for (int j_ = 0; j_ < 2; j_++) {                \
            const u16* p_ = (base) + ((nh) * 32 + j_ * 16) * 64;          \
            arr[j_][0] = *(const bf16x8*)(p_ + c0);                       \
            arr[j_][1] = *(const bf16x8*)(p_ + c1);                       \
        } } while (0)
#define MFMA_Q(mh, nh, arr) do {                                          \
        __builtin_amdgcn_s_setprio(1);                                    \
        _Pragma("unroll") for (int i_ = 0; i_ < 4; i_++)                  \
        _Pragma("unroll") for (int j_ = 0; j_ < 2; j_++) {                \
            f32x4 v_ = acc[(mh) * 4 + i_][(nh) * 2 + j_];                 \
            v_ = __builtin_amdgcn_mfma_f32_16x16x32_bf16(                 \
                     aF[i_][0], arr[j_][0], v_, 0, 0, 0);                 \
            v_ = __builtin_amdgcn_mfma_f32_16x16x32_bf16(                 \
                     aF[i_][1], arr[j_][1], v_, 0, 0, 0);                 \
            acc[(mh) * 4 + i_][(nh) * 2 + j_] = v_;                       \
        }                                                                 \
        __builtin_amdgcn_s_setprio(0);                                    \
    } while (0)

    const int NT = K >> 6;
    const int NITER = NT >> 1;

    STAGE_A(0, 0, 0); STAGE_A(0, 1, 0); STAGE_B(0, 0, 0); STAGE_B(0, 1, 0);
    if (NT > 1) {
        STAGE_A(1, 0, 64); STAGE_B(1, 0, 64); STAGE_B(1, 1, 64);
        asm volatile("s_waitcnt vmcnt(6)" ::: "memory");
    } else {
        asm volatile("s_waitcnt vmcnt(0)" ::: "memory");
    }
    CFENCE; BARRIER; CFENCE;

    for (int it = 0; it < NITER; it++) {
        const int t = it * 2;
        const int k1 = (t + 1) * 64, k2 = (t + 2) * 64, k3 = (t + 3) * 64;

        DS_A(aRd0, 0); DS_B(bRd0, 0, bF0);
        if (t + 1 < NT) STAGE_A(1, 1, k1);
        CFENCE; BARRIER; CFENCE;
        MFMA_Q(0, 0, bF0);
        CFENCE; BARRIER; CFENCE;

        DS_B(bRd0, 1, bF1);
        if (t + 2 < NT) STAGE_A(0, 0, k2);
        CFENCE; BARRIER; CFENCE;
        MFMA_Q(0, 1, bF1);
        CFENCE; BARRIER; CFENCE;

        DS_A(aRd0, 1);
        if (t + 2 < NT) STAGE_B(0, 0, k2);
        CFENCE; BARRIER; CFENCE;
        MFMA_Q(1, 0, bF0);
        CFENCE; BARRIER; CFENCE;

        if (t + 2 < NT) STAGE_B(0, 1, k2);
        if (it + 1 == NITER) asm volatile("s_waitcnt vmcnt(0)" ::: "memory");
        else                 asm volatile("s_waitcnt vmcnt(6)" ::: "memory");
        CFENCE; BARRIER; CFENCE;
        MFMA_Q(1, 1, bF1);
        CFENCE; BARRIER; CFENCE;

        DS_A(aRd1, 0); DS_B(bRd1, 0, bF0);
        if (t + 2 < NT) STAGE_A(0, 1, k2);
        CFENCE; BARRIER; CFENCE;
        MFMA_Q(0, 0, bF0);
        CFENCE; BARRIER; CFENCE;

        DS_B(bRd1, 1, bF1);
        if (t + 3 < NT) STAGE_A(1, 0, k3);
        CFENCE; BARRIER; CFENCE;
        MFMA_Q(0, 1, bF1);
        CFENCE; BARRIER; CFENCE;

        DS_A(aRd1, 1);
        if (t + 3 < NT) STAGE_B(1, 0, k3);
        CFENCE; BARRIER; CFENCE;
        MFMA_Q(1, 0, bF0);
        CFENCE; BARRIER; CFENCE;

        if (t + 3 < NT) STAGE_B(1, 1, k3);
        if (it + 1 < NITER) asm volatile("s_waitcnt vmcnt(6)" ::: "memory");
        CFENCE; BARRIER; CFENCE;
        MFMA_Q(1, 1, bF1);
        CFENCE; BARRIER; CFENCE;
    }

#undef STAGE_A
#undef STAGE_B
#undef DS_A
#undef DS_B
#undef MFMA_Q

    const long long crow0 = (long long)bm * 256 + wm * 128 + fq * 4;
    const int ccol0 = bn * 256 + wn * 64 + fr;
#pragma unroll
    for (int i = 0; i < 8; i++) {
#pragma unroll
        for (int r = 0; r < 4; r++) {
            const long long row = crow0 + i * 16 + r;
#pragma unroll
            for (int j = 0; j < 4; j++) {
                const int col = ccol0 + j * 16;
                const float bv = bf2f(bias[col]);
                C[row * ldc + col] = f2bf(acc[i][j][r] * scale + bv);
            }
        }
    }
}

// ---------------------------------------------------------------------------
// In-place row softmax over 1024 bf16 elements. One wave per row.
// ---------------------------------------------------------------------------
__global__ __launch_bounds__(256) void softmax_kernel(u16* __restrict__ S)
{
    const int tid = threadIdx.x, lane = tid & 63, wave = tid >> 6;
    const long long row = (long long)blockIdx.x * 4 + wave;
    u16* p = S + row * 1024 + lane * 16;
    union { uint4 q[2]; u16 u[16]; } d;
    d.q[0] = *(const uint4*)p;
    d.q[1] = *(const uint4*)(p + 8);
    float x[16];
    float mx = -1e30f;
#pragma unroll
    for (int j = 0; j < 16; j++) { x[j] = bf2f(d.u[j]); mx = fmaxf(mx, x[j]); }
#pragma unroll
    for (int m = 1; m < 64; m <<= 1) mx = fmaxf(mx, __shfl_xor(mx, m));
    float s = 0.f;
#pragma unroll
    for (int j = 0; j < 16; j++) { x[j] = __expf(x[j] - mx); s += x[j]; }
#pragma unroll
    for (int m = 1; m < 64; m <<= 1) s += __shfl_xor(s, m);
    const float inv = 1.0f / s;
#pragma unroll
    for (int j = 0; j < 16; j++) d.u[j] = f2bf(x[j] * inv);
    *(uint4*)p = d.q[0];
    *(uint4*)(p + 8) = d.q[1];
}

// ---------------------------------------------------------------------------
// LayerNorm(obj + I) * g + b -> out. One block per row (objMask variant).
// ---------------------------------------------------------------------------
__global__ __launch_bounds__(256) void ln_kernel(
    const u16* __restrict__ obj, const u16* __restrict__ gam,
    const u16* __restrict__ bet, const u16* __restrict__ I,
    void* __restrict__ outv, long long outOff, int objMask,
    const int* __restrict__ flag)
{
    __shared__ float red[8];
    const int tid = threadIdx.x, lane = tid & 63, wave = tid >> 6;
    const long long base = (long long)blockIdx.x * 1024;
    const long long obase = (long long)(blockIdx.x & objMask) * 1024;
    const int c = tid * 4;
    union { uint2 q; u16 u[4]; } ov, iv, gv, bv;
    ov.q = *(const uint2*)(obj + obase + c);
    iv.q = *(const uint2*)(I + base + c);
    float x[4], s = 0.f, sq = 0.f;
#pragma unroll
    for (int j = 0; j < 4; j++) {
        x[j] = bf2f(ov.u[j]) + bf2f(iv.u[j]);
        s += x[j]; sq += x[j] * x[j];
    }
#pragma unroll
    for (int m = 1; m < 64; m <<= 1) {
        s += __shfl_xor(s, m);
        sq += __shfl_xor(sq, m);
    }
    if (lane == 0) { red[wave] = s; red[4 + wave] = sq; }
    __syncthreads();
    s = red[0] + red[1] + red[2] + red[3];
    sq = red[4] + red[5] + red[6] + red[7];
    const float mu = s * (1.0f / 1024.0f);
    const float var = fmaxf(sq * (1.0f / 1024.0f) - mu * mu, 0.0f);
    const float rs = rsqrtf(var + 1e-5f);
    gv.q = *(const uint2*)(gam + c);
    bv.q = *(const uint2*)(bet + c);
    float y[4];
#pragma unroll
    for (int j = 0; j < 4; j++)
        y[j] = (x[j] - mu) * rs * bf2f(gv.u[j]) + bf2f(bv.u[j]);
    if (flag[0]) {
        float4 w; w.x = y[0]; w.y = y[1]; w.z = y[2]; w.w = y[3];
        *(float4*)((float*)outv + outOff + base + c) = w;
    } else {
        union { uint2 q; u16 u[4]; } wv;
#pragma unroll
        for (int j = 0; j < 4; j++) wv.u[j] = f2bf(y[j]);
        *(uint2*)((u16*)outv + outOff + base + c) = wv.q;
    }
}

// ---------------------------------------------------------------------------
// Merged LayerNorm, BOTH sides per row: reads obj once, I1 and I2 = I+iOff,
// writes out row and out row+oOff. One block per row (16384 blocks).
// ---------------------------------------------------------------------------
__global__ __launch_bounds__(256) void ln2_kernel(
    const u16* __restrict__ obj, const u16* __restrict__ gam,
    const u16* __restrict__ bet, const u16* __restrict__ I, long long iOff,
    void* __restrict__ outv, long long oOff, const int* __restrict__ flag)
{
    __shared__ float red[16];
    const int tid = threadIdx.x, lane = tid & 63, wave = tid >> 6;
    const long long base = (long long)blockIdx.x * 1024;
    const int c = tid * 4;
    union { uint2 q; u16 u[4]; } ov, i1, i2, gv, bv;
    ov.q = *(const uint2*)(obj + base + c);
    i1.q = *(const uint2*)(I + base + c);
    i2.q = *(const uint2*)(I + iOff + base + c);
    float x1[4], x2[4], s1 = 0.f, q1 = 0.f, s2 = 0.f, q2 = 0.f;
#pragma unroll
    for (int j = 0; j < 4; j++) {
        const float o = bf2f(ov.u[j]);
        x1[j] = o + bf2f(i1.u[j]);
        x2[j] = o + bf2f(i2.u[j]);
        s1 += x1[j]; q1 += x1[j] * x1[j];
        s2 += x2[j]; q2 += x2[j] * x2[j];
    }
#pragma unroll
    for (int m = 1; m < 64; m <<= 1) {
        s1 += __shfl_xor(s1, m); q1 += __shfl_xor(q1, m);
        s2 += __shfl_xor(s2, m); q2 += __shfl_xor(q2, m);
    }
    if (lane == 0) {
        red[wave] = s1; red[4 + wave] = q1;
        red[8 + wave] = s2; red[12 + wave] = q2;
    }
    __syncthreads();
    s1 = red[0] + red[1] + red[2] + red[3];
    q1 = red[4] + red[5] + red[6] + red[7];
    s2 = red[8] + red[9] + red[10] + red[11];
    q2 = red[12] + red[13] + red[14] + red[15];
    const float mu1 = s1 * (1.0f / 1024.0f);
    const float rs1 = rsqrtf(fmaxf(q1 * (1.0f / 1024.0f) - mu1 * mu1, 0.0f)
                             + 1e-5f);
    const float mu2 = s2 * (1.0f / 1024.0f);
    const float rs2 = rsqrtf(fmaxf(q2 * (1.0f / 1024.0f) - mu2 * mu2, 0.0f)
                             + 1e-5f);
    gv.q = *(const uint2*)(gam + c);
    bv.q = *(const uint2*)(bet + c);
    float y1[4], y2[4];
#pragma unroll
    for (int j = 0; j < 4; j++) {
        const float g = bf2f(gv.u[j]), b = bf2f(bv.u[j]);
        y1[j] = (x1[j] - mu1) * rs1 * g + b;
        y2[j] = (x2[j] - mu2) * rs2 * g + b;
    }
    if (flag[0]) {
        float4 w1, w2;
        w1.x = y1[0]; w1.y = y1[1]; w1.z = y1[2]; w1.w = y1[3];
        w2.x = y2[0]; w2.y = y2[1]; w2.z = y2[2]; w2.w = y2[3];
        *(float4*)((float*)outv + base + c) = w1;
        *(float4*)((float*)outv + oOff + base + c) = w2;
    } else {
        union { uint2 q; u16 u[4]; } w1, w2;
#pragma unroll
        for (int j = 0; j < 4; j++) { w1.u[j] = f2bf(y1[j]); w2.u[j] = f2bf(y2[j]); }
        *(uint2*)((u16*)outv + base + c) = w1.q;
        *(uint2*)((u16*)outv + oOff + base + c) = w2.q;
    }
}

// ---------------------------------------------------------------------------
extern "C" void kernel_launch(void* const* d_in, const int* in_sizes, int n_in,
                              void* d_out, int out_size, void* d_ws, size_t ws_size,
                              hipStream_t stream)
{
    u16* ws = (u16*)d_ws;
    int* flag = (int*)d_ws;              // header: first 64 bytes
    const dim3 blk(256);
    const dim3 blk5(512);
    const float scale = 0.03125f;        // 1024^-0.5
    const long long Eobj = 16777216;     // 8*2048*1024
    const long long Ekv  = 8388608;      // 8*1024*1024
    const long long sQ = 2048LL * 1024, sK = 1024LL * 1024;
    const int ALLZ = 255;                // zAmask: full z indexing
    const int NOZ = -1;                  // zShift: use blockIdx.z

    detect_kernel<<<dim3(1), blk, 0, stream>>>((const u16*)d_in[0], flag);

    // merged conversion into contiguous region after 64B header
    const size_t wsElems = ws_size / 2;
    ConvArgs ca;
    long long cur = 32;
    u16* cIn[15];
    for (int i = 0; i < 15; i++) {
        ca.src[i] = d_in[i];
        ca.off[i] = cur - 32;
        cIn[i] = ws + cur;
        cur += in_sizes[i];
    }
    ca.off[15] = cur - 32;
    const long long convTotal = cur - 32;
    const bool canConv = wsElems >= (size_t)(32 + convTotal + 8388608 + 32);
    if (canConv) {
        const int grid = (int)((convTotal / 8 + 255) / 256);
        convert_all_kernel<<<dim3(grid), blk, 0, stream>>>(ca, ws + 32, flag);
    } else {
        for (int i = 0; i < 15; i++) cIn[i] = (u16*)d_in[i];
        cur = 32;
    }
    const u16* obj = cIn[0];  const u16* sub = cIn[1];  const u16* scene = cIn[2];
    const u16* W_q = cIn[3];  const u16* b_q = cIn[4];
    const u16* W_sk = cIn[5]; const u16* b_sk = cIn[6];
    const u16* W_sv = cIn[7]; const u16* b_sv = cIn[8];
    const u16* W_ek = cIn[9]; const u16* b_ek = cIn[10];
    const u16* W_ev = cIn[11]; const u16* b_ev = cIn[12];
    const u16* ln_g = cIn[13]; const u16* ln_b = cIn[14];

    // planMerged: both attention sides in single dispatches (S,O doubled)
    const bool planMerged = canConv &&
        wsElems >= (size_t)(cur + 5 * Eobj + 4 * Ekv);
    const bool planComb = canConv &&
        wsElems >= (size_t)(cur + 3 * Eobj + 4 * Ekv);
    const bool planA = wsElems >= (size_t)(cur + 3 * Eobj + 2 * Ekv);

    if (planMerged) {
        u16* Q  = ws + cur;          // Eobj      (contiguous with Kb below)
        u16* Kb = Q + Eobj;          // 2*Ekv : [a][z][1024][1024]
        u16* VT = Kb + 2 * Ekv;      // 2*Ekv : VT[p][a*8192 + z*1024 + s]
        u16* S  = VT + 2 * Ekv;      // 2*Eobj: [a][z][2048][1024]
        u16* O  = S + 2 * Eobj;      // 2*Eobj

        // Merged Q+K projection: A = [obj;sub;scene] (contiguous, 32768 rows),
        // C = [Q;Kb] (contiguous), 3-way W select by bm (64/96 of nbm=128).
        gemm256p3_kernel<<<dim3(512, 1, 1), blk5, 0, stream>>>(
            obj, W_q, Q, b_q, W_sk, b_sk, W_ek, b_ek,
            1.0f, 2, 1024, 1024, 1024, 1024);
        // VT[p][n] = {W_sv|W_ev}[p,:] . [sub;scene][n,:] + bias (dual bn)
        gemm256_kernel<<<dim3(256, 1, 1), blk5, 0, stream>>>(
            W_sv, sub, VT, b_sv, W_ev, b_ev,
            1.0f, 2, 2, 6, ALLZ, NOZ, 1024, 1024, 16384, 1024, 0, 0, 0);

        // S[a][z] = Q[z] . Kb[a][z]^T : flattened z'=id>>5, A indexed z'&7
        gemm256_kernel<<<dim3(512, 1, 1), blk5, 0, stream>>>(
            Q, Kb, S, nullptr, nullptr, nullptr,
            scale, 0, 0, 2, 7, 5, 1024, 1024, 1024, 1024, sQ, sK, sQ);
        softmax_kernel<<<dim3(8192), blk, 0, stream>>>(S);
        // O[a][z] = S[a][z] . V; VT col offset z'*1024
        gemm256_kernel<<<dim3(512, 1, 1), blk5, 0, stream>>>(
            S, VT, O, nullptr, nullptr, nullptr,
            1.0f, 0, 0, 2, ALLZ, 5, 1024, 16384, 1024, 1024, sQ, 1024, sQ);
        // Merged LN: both sides per row, obj read once
        ln2_kernel<<<dim3(16384), blk, 0, stream>>>(
            obj, ln_g, ln_b, O, Eobj, d_out, Eobj, flag);
    } else if (planComb) {
        u16* Q  = ws + cur;          // Eobj
        u16* Kb = Q + Eobj;          // 2*Ekv
        u16* VT = Kb + 2 * Ekv;      // 2*Ekv
        u16* S  = VT + 2 * Ekv;      // Eobj
        u16* O  = S + Eobj;          // Eobj

        gemm256p3_kernel<<<dim3(512, 1, 1), blk5, 0, stream>>>(
            obj, W_q, Q, b_q, W_sk, b_sk, W_ek, b_ek,
            1.0f, 2, 1024, 1024, 1024, 1024);
        gemm256_kernel<<<dim3(256, 1, 1), blk5, 0, stream>>>(
            W_sv, sub, VT, b_sv, W_ev, b_ev,
            1.0f, 2, 2, 6, ALLZ, NOZ, 1024, 1024, 16384, 1024, 0, 0, 0);

        for (int a = 0; a < 2; a++) {
            gemm256_kernel<<<dim3(32, 1, 8), blk5, 0, stream>>>(
                Q, Kb + (long long)a * Ekv, S, nullptr, nullptr, nullptr,
                scale, 0, 0, 2, ALLZ, NOZ, 1024, 1024, 1024, 1024, sQ, sK, sQ);
            softmax_kernel<<<dim3(4096), blk, 0, stream>>>(S);
            gemm256_kernel<<<dim3(32, 1, 8), blk5, 0, stream>>>(
                S, VT + a * 8192, O, nullptr, nullptr, nullptr,
                1.0f, 0, 0, 2, ALLZ, NOZ, 1024, 16384, 1024, 1024, sQ, 1024, sQ);
            ln_kernel<<<dim3(16384), blk, 0, stream>>>(
                obj, ln_g, ln_b, O, d_out, (long long)a * Eobj, 0x7fffffff,
                flag);
        }
    } else if (planA) {
        u16* Q  = ws + cur;
        u16* Kb = Q + Eobj;
        u16* VT = Kb + Ekv;
        u16* S  = VT + Ekv;
        u16* O  = S + Eobj;

        gemm256_kernel<<<dim3(256, 1, 1), blk5, 0, stream>>>(
            obj, W_q, Q, b_q, nullptr, nullptr,
            1.0f, 1, 0, 2, ALLZ, NOZ, 1024, 1024, 1024, 1024, 0, 0, 0);

        for (int a = 0; a < 2; a++) {
            const u16* X  = a ? scene : sub;
            const u16* Wk = a ? W_ek : W_sk;
            const u16* bk = a ? b_ek : b_sk;
            const u16* Wv = a ? W_ev : W_sv;
            const u16* bv = a ? b_ev : b_sv;

            gemm256_kernel<<<dim3(128, 1, 1), blk5, 0, stream>>>(
                X, Wk, Kb, bk, nullptr, nullptr,
                1.0f, 1, 0, 2, ALLZ, NOZ, 1024, 1024, 1024, 1024, 0, 0, 0);
            gemm256_kernel<<<dim3(128, 1, 1), blk5, 0, stream>>>(
                Wv, X, VT, bv, nullptr, nullptr,
                1.0f, 2, 0, 5, ALLZ, NOZ, 1024, 1024, 8192, 1024, 0, 0, 0);
            gemm256_kernel<<<dim3(32, 1, 8), blk5, 0, stream>>>(
                Q, Kb, S, nullptr, nullptr, nullptr,
                scale, 0, 0, 2, ALLZ, NOZ, 1024, 1024, 1024, 1024, sQ, sK, sQ);
            softmax_kernel<<<dim3(4096), blk, 0, stream>>>(S);
            gemm256_kernel<<<dim3(32, 1, 8), blk5, 0, stream>>>(
                S, VT, O, nullptr, nullptr, nullptr,
                1.0f, 0, 0, 2, ALLZ, NOZ, 1024, 8192, 1024, 1024, sQ, 1024, sQ);
            ln_kernel<<<dim3(16384), blk, 0, stream>>>(
                obj, ln_g, ln_b, O, d_out, (long long)a * Eobj, 0x7fffffff,
                flag);
        }
    } else {
        // per-batch fallback: 8.39M elems of pipeline scratch
        u16* Qb = ws + cur;              // 2M
        u16* Kb = Qb + 2097152;          // 1M
        u16* VT = Kb + 1048576;          // 1M
        u16* S  = VT + 1048576;          // 2M
        u16* O  = S + 2097152;           // 2M

        for (int a = 0; a < 2; a++) {
            const u16* X  = a ? scene : sub;
            const u16* Wk = a ? W_ek : W_sk;
            const u16* bk = a ? b_ek : b_sk;
            const u16* Wv = a ? W_ev : W_sv;
            const u16* bv = a ? b_ev : b_sv;

            for (int z = 0; z < 8; z++) {
                const u16* objz = obj + (long long)z * sQ;
                const u16* Xz   = X + (long long)z * sK;
                gemm256_kernel<<<dim3(32, 1, 1), blk5, 0, stream>>>(
                    objz, W_q, Qb, b_q, nullptr, nullptr,
                    1.0f, 1, 0, 2, ALLZ, NOZ, 1024, 1024, 1024, 1024, 0, 0, 0);
                gemm256_kernel<<<dim3(16, 1, 1), blk5, 0, stream>>>(
                    Xz, Wk, Kb, bk, nullptr, nullptr,
                    1.0f, 1, 0, 2, ALLZ, NOZ, 1024, 1024, 1024, 1024, 0, 0, 0);
                gemm256_kernel<<<dim3(16, 1, 1), blk5, 0, stream>>>(
                    Wv, Xz, VT, bv, nullptr, nullptr,
                    1.0f, 2, 0, 2, ALLZ, NOZ, 1024, 1024, 1024, 1024, 0, 0, 0);
                gemm256_kernel<<<dim3(32, 1, 1), blk5, 0, stream>>>(
                    Qb, Kb, S, nullptr, nullptr, nullptr,
                    scale, 0, 0, 2, ALLZ, NOZ, 1024, 1024, 1024, 1024, 0, 0, 0);
                softmax_kernel<<<dim3(512), blk, 0, stream>>>(S);
                gemm256_kernel<<<dim3(32, 1, 1), blk5, 0, stream>>>(
                    S, VT, O, nullptr, nullptr, nullptr,
                    1.0f, 0, 0, 2, ALLZ, NOZ, 1024, 1024, 1024, 1024, 0, 0, 0);
                ln_kernel<<<dim3(2048), blk, 0, stream>>>(
                    objz, ln_g, ln_b, O, d_out,
                    (long long)a * Eobj + (long long)z * sQ, 0x7fffffff,
                    flag);
            }
        }
    }

    (void)n_in; (void)out_size;
}

// Round 13
// 579.286 us; speedup vs baseline: 1.0585x; 1.0017x over previous
//
#include <hip/hip_runtime.h>

typedef unsigned short u16;
typedef short bf16x8 __attribute__((ext_vector_type(8)));
typedef float f32x4 __attribute__((ext_vector_type(4)));

__device__ __forceinline__ float bf2f(u16 s) {
    union { unsigned u; float f; } v;
    v.u = ((unsigned)s) << 16;
    return v.f;
}
__device__ __forceinline__ u16 f2bf(float f) {
    union { float f; unsigned u; } v;
    v.f = f;
    unsigned r = v.u + 0x7fffu + ((v.u >> 16) & 1u);  // RNE
    return (u16)(r >> 16);
}

#define GLD16(gp, lp)                                                  \
    __builtin_amdgcn_global_load_lds(                                  \
        (__attribute__((address_space(1))) void*)(gp),                 \
        (__attribute__((address_space(3))) void*)(lp), 16, 0, 0)

#define CFENCE asm volatile("" ::: "memory")
#define BARRIER __builtin_amdgcn_s_barrier()

// ---------------------------------------------------------------------------
// Detect whether d_in[0] is f32 (flag=1) or bf16 (flag=0).
// ---------------------------------------------------------------------------
__global__ __launch_bounds__(256) void detect_kernel(
    const u16* __restrict__ src, int* __restrict__ flag)
{
    __shared__ int red[4];
    const int tid = threadIdx.x;
    int cnt = 0;
    for (int j = 0; j < 64; j++) {
        const u16 v = src[tid * 64 + j];
        const int e = (v >> 7) & 0xFF;
        cnt += (e >= 0x90) ? 1 : 0;
    }
#pragma unroll
    for (int m = 1; m < 64; m <<= 1) cnt += __shfl_xor(cnt, m);
    if ((tid & 63) == 0) red[tid >> 6] = cnt;
    __syncthreads();
    if (tid == 0) {
        const int total = red[0] + red[1] + red[2] + red[3];
        flag[0] = (total > 1024) ? 1 : 0;
    }
}

// ---------------------------------------------------------------------------
// Single merged conversion: all 15 inputs -> contiguous bf16 region in ws.
// ---------------------------------------------------------------------------
struct ConvArgs {
    const void* src[15];
    long long   off[16];   // cumulative element offsets in dst (off[15]=total)
};

__global__ __launch_bounds__(256) void convert_all_kernel(
    ConvArgs a, u16* __restrict__ dst, const int* __restrict__ flag)
{
    const long long i = ((long long)blockIdx.x * 256 + threadIdx.x) * 8;
    if (i >= a.off[15]) return;
    int s = 0;
#pragma unroll
    for (int t = 1; t < 15; t++) s += (i >= a.off[t]) ? 1 : 0;
    const long long local = i - a.off[s];
    union { uint4 q; u16 u[8]; } o;
    if (flag[0]) {
        const float* sp = (const float*)a.src[s] + local;
        const float4 x = *(const float4*)sp;
        const float4 y = *(const float4*)(sp + 4);
        o.u[0] = f2bf(x.x); o.u[1] = f2bf(x.y);
        o.u[2] = f2bf(x.z); o.u[3] = f2bf(x.w);
        o.u[4] = f2bf(y.x); o.u[5] = f2bf(y.y);
        o.u[6] = f2bf(y.z); o.u[7] = f2bf(y.w);
    } else {
        o.q = *(const uint4*)((const u16*)a.src[s] + local);
    }
    *(uint4*)(dst + i) = o.q;
}

// ---------------------------------------------------------------------------
// 256x256-tile GEMM, 8-phase pipelined schedule (T1+T2+T3+T4+T5).
// *** BYTE-EXACT round-4 kernel (QK/PV = ~80us, MfmaUtil 34%). FROZEN:
// *** any body edit (params, waits) measurably regressed the K-loop
// *** schedule (r9: +35%, r12 restore confirmed). Do not touch.
//   C[M,N](bf16) = scale * (A[M,K] . B[N,K]^T) + bias
// 512 threads = 8 waves (2 M x 4 N), per-wave 128x64 via 8x4 MFMA 16x16x32.
// BK=64, LDS = 2 buffers x (A 32KB + B 32KB) = 128KB -> 1 block/CU.
// Staging: global_load_lds w=16, linear LDS dest, XOR col-block swizzle on
//   the GLOBAL source address -> conflict-free ds_read_b128 (measured 0).
// Schedule per iteration (2 K-tiles): 8 phases; counted vmcnt(6) at
//   phases 4 & 8 only; no explicit lgkmcnt (compiler places them better).
// dualMode: 1 = {B,bias}->alt when bm>=nbm/2; 2 = {A,bias}->alt bn>=nbn/2.
// bias_mode: 0 none, 1 bias[col], 2 bias[row].
// Batching: zShift>=0 -> z = swizzled_id >> zShift; else z = blockIdx.z.
//   A += (z & zAmask)*sA, B += z*sB, C += z*sC.
// ---------------------------------------------------------------------------
__global__ __launch_bounds__(512, 2) void gemm256_kernel(
    const u16* __restrict__ A, const u16* __restrict__ B,
    u16* __restrict__ C, const u16* __restrict__ bias,
    const u16* __restrict__ alt, const u16* __restrict__ biasAlt,
    float scale, int bias_mode, int dualMode, int nbnShift, int zAmask,
    int zShift,
    int lda, int ldb, int ldc, int K,
    long long sA, long long sB, long long sC)
{
    __shared__ alignas(16) u16 lds[4][256 * 64];  // [buf*2 + op], 128 KB

    const int tid  = threadIdx.x;
    const int lane = tid & 63;
    const int wave = tid >> 6;
    const int wm   = wave >> 2;      // 0..1
    const int wn   = wave & 3;       // 0..3

    // T1: bijective XCD swizzle (m204) over the full flattened grid
    const int nwg = gridDim.x;
    int id = blockIdx.x;
    if (nwg >= 8) {
        const int q = nwg >> 3, r = nwg & 7;
        const int x = id & 7, sidx = id >> 3;
        id = (x < r ? x * (q + 1) : r * (q + 1) + (x - r) * q) + sidx;
    }
    int z, rem;
    if (zShift >= 0) { z = id >> zShift; rem = id & ((1 << zShift) - 1); }
    else             { z = blockIdx.z;   rem = id; }
    const int nbn = 1 << nbnShift;
    const int bm = rem >> nbnShift, bn = rem & (nbn - 1);
    const int nbm = ((zShift >= 0) ? (1 << zShift) : nwg) >> nbnShift;

    if (dualMode == 1 && bm >= (nbm >> 1)) { B = alt; bias = biasAlt; }
    if (dualMode == 2 && bn >= (nbn >> 1)) { A = alt; bias = biasAlt; }

    A += (long long)(z & zAmask) * sA;
    B += (long long)z * sB;
    C += (long long)z * sC;

    // ---- staging addresses (per-lane global, wave-uniform LDS base) ----
    const int rw  = lane >> 3;           // 0..7 row within wave chunk
    const int cb  = lane & 7;            // LDS col-block
    const int scb = cb ^ rw;             // swizzled GLOBAL col-block
    const int srow = wave * 8 + rw;      // 0..63
    const int bRowBase = ((wave & 4) << 4) + ((wave & 3) << 3);

    const u16* aG = A + (long long)(bm * 256 + srow) * lda + scb * 8;
    const u16* bG = B + (long long)(bn * 256 + bRowBase + rw) * ldb + scb * 8;
    const long long a64  = (long long)64 * lda;
    const long long a128 = (long long)128 * lda;
    const long long b32  = (long long)32 * ldb;
    const long long b128 = (long long)128 * ldb;

#define STAGE_A(buf, mh, k0) do {                                         \
        u16* d_ = &lds[(buf) * 2][((mh) * 64 + wave * 8) * 64];           \
        GLD16(aG + (k0) + ((mh) ? a64 : 0), d_);                          \
        GLD16(aG + (k0) + ((mh) ? a64 : 0) + a128, d_ + 128 * 64);        \
    } while (0)
#define STAGE_B(buf, nh, k0) do {                                         \
        u16* d_ = &lds[(buf) * 2 + 1][(bRowBase + (nh) * 32) * 64];       \
        GLD16(bG + (k0) + ((nh) ? b32 : 0), d_);                          \
        GLD16(bG + (k0) + ((nh) ? b32 : 0) + b128, d_ + 128 * 64);        \
    } while (0)

    // ---- fragment read addressing (XOR-unswizzle on read) ----
    const int fr = lane & 15, fq = lane >> 4;
    const int c0 = ((fq ^ (fr & 7)) << 3);
    const int c1 = (((4 | fq) ^ (fr & 7)) << 3);
    const u16* aRd0 = &lds[0][(wm * 128 + fr) * 64];
    const u16* aRd1 = &lds[2][(wm * 128 + fr) * 64];
    const u16* bRd0 = &lds[1][(wn * 64 + fr) * 64];
    const u16* bRd1 = &lds[3][(wn * 64 + fr) * 64];

    bf16x8 aF[4][2], bF0[2][2], bF1[2][2];
    f32x4 acc[8][4];
#pragma unroll
    for (int i = 0; i < 8; i++)
#pragma unroll
        for (int j = 0; j < 4; j++) {
            acc[i][j][0] = 0.f; acc[i][j][1] = 0.f;
            acc[i][j][2] = 0.f; acc[i][j][3] = 0.f;
        }

#define DS_A(base, mh) do {                                               \
        _Pragma("unroll") for (int i_ = 0; i_ < 4; i_++) {                \
            const u16* p_ = (base) + ((mh) * 64 + i_ * 16) * 64;          \
            aF[i_][0] = *(const bf16x8*)(p_ + c0);                        \
            aF[i_][1] = *(const bf16x8*)(p_ + c1);                        \
        } } while (0)
#define DS_B(base, nh, arr) do {                                          \
        _Pragma("unroll") for (int j_ = 0; j_ < 2; j_++) {                \
            const u16* p_ = (base) + ((nh) * 32 + j_ * 16) * 64;          \
            arr[j_][0] = *(const bf16x8*)(p_ + c0);                       \
            arr[j_][1] = *(const bf16x8*)(p_ + c1);                       \
        } } while (0)
#define MFMA_Q(mh, nh, arr) do {                                          \
        __builtin_amdgcn_s_setprio(1);                                    \
        _Pragma("unroll") for (int i_ = 0; i_ < 4; i_++)                  \
        _Pragma("unroll") for (int j_ = 0; j_ < 2; j_++) {                \
            f32x4 v_ = acc[(mh) * 4 + i_][(nh) * 2 + j_];                 \
            v_ = __builtin_amdgcn_mfma_f32_16x16x32_bf16(                 \
                     aF[i_][0], arr[j_][0], v_, 0, 0, 0);                 \
            v_ = __builtin_amdgcn_mfma_f32_16x16x32_bf16(                 \
                     aF[i_][1], arr[j_][1], v_, 0, 0, 0);                 \
            acc[(mh) * 4 + i_][(nh) * 2 + j_] = v_;                       \
        }                                                                 \
        __builtin_amdgcn_s_setprio(0);                                    \
    } while (0)

    const int NT = K >> 6;        // K / 64, assumed even and >= 2
    const int NITER = NT >> 1;

    // ---- prologue: tile0 full -> buf0; tile1 {A-mh0, B-nh0, B-nh1} -> buf1
    STAGE_A(0, 0, 0); STAGE_A(0, 1, 0); STAGE_B(0, 0, 0); STAGE_B(0, 1, 0);
    if (NT > 1) {
        STAGE_A(1, 0, 64); STAGE_B(1, 0, 64); STAGE_B(1, 1, 64);
        asm volatile("s_waitcnt vmcnt(6)" ::: "memory");
    } else {
        asm volatile("s_waitcnt vmcnt(0)" ::: "memory");
    }
    CFENCE; BARRIER; CFENCE;

    for (int it = 0; it < NITER; it++) {
        const int t = it * 2;
        const int k1 = (t + 1) * 64, k2 = (t + 2) * 64, k3 = (t + 3) * 64;

        // phase 1: buf0 (mh0,nh0); stage A-mh1 -> buf1 (tile t+1)
        DS_A(aRd0, 0); DS_B(bRd0, 0, bF0);
        if (t + 1 < NT) STAGE_A(1, 1, k1);
        CFENCE; BARRIER; CFENCE;
        MFMA_Q(0, 0, bF0);
        CFENCE; BARRIER; CFENCE;

        // phase 2: buf0 (mh0,nh1); stage A-mh0 -> buf0 (tile t+2)
        DS_B(bRd0, 1, bF1);
        if (t + 2 < NT) STAGE_A(0, 0, k2);
        CFENCE; BARRIER; CFENCE;
        MFMA_Q(0, 1, bF1);
        CFENCE; BARRIER; CFENCE;

        // phase 3: buf0 (mh1,nh0); stage B-nh0 -> buf0 (tile t+2)
        DS_A(aRd0, 1);
        if (t + 2 < NT) STAGE_B(0, 0, k2);
        CFENCE; BARRIER; CFENCE;
        MFMA_Q(1, 0, bF0);
        CFENCE; BARRIER; CFENCE;

        // phase 4: buf0 (mh1,nh1); stage B-nh1 -> buf0 (tile t+2); vmcnt
        if (t + 2 < NT) STAGE_B(0, 1, k2);
        if (it + 1 == NITER) asm volatile("s_waitcnt vmcnt(0)" ::: "memory");
        else                 asm volatile("s_waitcnt vmcnt(6)" ::: "memory");
        CFENCE; BARRIER; CFENCE;
        MFMA_Q(1, 1, bF1);
        CFENCE; BARRIER; CFENCE;

        // phase 5: buf1 (mh0,nh0); stage A-mh1 -> buf0 (tile t+2)
        DS_A(aRd1, 0); DS_B(bRd1, 0, bF0);
        if (t + 2 < NT) STAGE_A(0, 1, k2);
        CFENCE; BARRIER; CFENCE;
        MFMA_Q(0, 0, bF0);
        CFENCE; BARRIER; CFENCE;

        // phase 6: buf1 (mh0,nh1); stage A-mh0 -> buf1 (tile t+3)
        DS_B(bRd1, 1, bF1);
        if (t + 3 < NT) STAGE_A(1, 0, k3);
        CFENCE; BARRIER; CFENCE;
        MFMA_Q(0, 1, bF1);
        CFENCE; BARRIER; CFENCE;

        // phase 7: buf1 (mh1,nh0); stage B-nh0 -> buf1 (tile t+3)
        DS_A(aRd1, 1);
        if (t + 3 < NT) STAGE_B(1, 0, k3);
        CFENCE; BARRIER; CFENCE;
        MFMA_Q(1, 0, bF0);
        CFENCE; BARRIER; CFENCE;

        // phase 8: buf1 (mh1,nh1); stage B-nh1 -> buf1 (tile t+3); vmcnt
        if (t + 3 < NT) STAGE_B(1, 1, k3);
        if (it + 1 < NITER) asm volatile("s_waitcnt vmcnt(6)" ::: "memory");
        CFENCE; BARRIER; CFENCE;
        MFMA_Q(1, 1, bF1);
        CFENCE; BARRIER; CFENCE;
    }

#undef STAGE_A
#undef STAGE_B
#undef DS_A
#undef DS_B
#undef MFMA_Q

    // ---- epilogue: C/D layout col=lane&15, row=quad*4+reg ----
    const long long crow0 = (long long)bm * 256 + wm * 128 + fq * 4;
    const int ccol0 = bn * 256 + wn * 64 + fr;
#pragma unroll
    for (int i = 0; i < 8; i++) {
#pragma unroll
        for (int r = 0; r < 4; r++) {
            const long long row = crow0 + i * 16 + r;
            const float bvr = (bias_mode == 2) ? bf2f(bias[row]) : 0.0f;
#pragma unroll
            for (int j = 0; j < 4; j++) {
                const int col = ccol0 + j * 16;
                const float bv = (bias_mode == 1) ? bf2f(bias[col]) : bvr;
                C[row * ldc + col] = f2bf(acc[i][j][r] * scale + bv);
            }
        }
    }
}

// ---------------------------------------------------------------------------
// Same GEMM with 3-way B/bias select by bm (merged Q+K projection ONLY).
// Separate kernel so the hot QK^T/PV kernel above stays byte-frozen.
// THIS ROUND: A/B experiment — vectorized epilogue via LDS staging
// (stride-68 slab, conflict-free scatter; 16 coalesced dwordx4 stores
// per thread instead of 128 scalar u16 stores).
// ---------------------------------------------------------------------------
__global__ __launch_bounds__(512, 2) void gemm256p3_kernel(
    const u16* __restrict__ A, const u16* __restrict__ B,
    u16* __restrict__ C, const u16* __restrict__ bias,
    const u16* __restrict__ alt, const u16* __restrict__ biasAlt,
    const u16* __restrict__ alt2, const u16* __restrict__ biasAlt2,
    float scale, int nbnShift,
    int lda, int ldb, int ldc, int K)
{
    __shared__ alignas(16) u16 lds[4][256 * 64];

    const int tid  = threadIdx.x;
    const int lane = tid & 63;
    const int wave = tid >> 6;
    const int wm   = wave >> 2;
    const int wn   = wave & 3;

    const int nwg = gridDim.x;
    int id = blockIdx.x;
    if (nwg >= 8) {
        const int q = nwg >> 3, r = nwg & 7;
        const int x = id & 7, sidx = id >> 3;
        id = (x < r ? x * (q + 1) : r * (q + 1) + (x - r) * q) + sidx;
    }
    const int nbn = 1 << nbnShift;
    const int bm = id >> nbnShift, bn = id & (nbn - 1);
    const int nbm = nwg >> nbnShift;

    if (bm >= 3 * (nbm >> 2))      { B = alt2; bias = biasAlt2; }
    else if (bm >= (nbm >> 1))     { B = alt;  bias = biasAlt; }

    const int rw  = lane >> 3;
    const int cb  = lane & 7;
    const int scb = cb ^ rw;
    const int srow = wave * 8 + rw;
    const int bRowBase = ((wave & 4) << 4) + ((wave & 3) << 3);

    const u16* aG = A + (long long)(bm * 256 + srow) * lda + scb * 8;
    const u16* bG = B + (long long)(bn * 256 + bRowBase + rw) * ldb + scb * 8;
    const long long a64  = (long long)64 * lda;
    const long long a128 = (long long)128 * lda;
    const long long b32  = (long long)32 * ldb;
    const long long b128 = (long long)128 * ldb;

#define STAGE_A(buf, mh, k0) do {                                         \
        u16* d_ = &lds[(buf) * 2][((mh) * 64 + wave * 8) * 64];           \
        GLD16(aG + (k0) + ((mh) ? a64 : 0), d_);                          \
        GLD16(aG + (k0) + ((mh) ? a64 : 0) + a128, d_ + 128 * 64);        \
    } while (0)
#define STAGE_B(buf, nh, k0) do {                                         \
        u16* d_ = &lds[(buf) * 2 + 1][(bRowBase + (nh) * 32) * 64];       \
        GLD16(bG + (k0) + ((nh) ? b32 : 0), d_);                          \
        GLD16(bG + (k0) + ((nh) ? b32 : 0) + b128, d_ + 128 * 64);        \
    } while (0)

    const int fr = lane & 15, fq = lane >> 4;
    const int c0 = ((fq ^ (fr & 7)) << 3);
    const int c1 = (((4 | fq) ^ (fr & 7)) << 3);
    const u16* aRd0 = &lds[0][(wm * 128 + fr) * 64];
    const u16* aRd1 = &lds[2][(wm * 128 + fr) * 64];
    const u16* bRd0 = &lds[1][(wn * 64 + fr) * 64];
    const u16* bRd1 = &lds[3][(wn * 64 + fr) * 64];

    bf16x8 aF[4][2], bF0[2][2], bF1[2][2];
    f32x4 acc[8][4];
#pragma unroll
    for (int i = 0; i < 8; i++)
#pragma unroll
        for (int j = 0; j < 4; j++) {
            acc[i][j][0] = 0.f; acc[i][j][1] = 0.f;
            acc[i][j][2] = 0.f; acc[i][j][3] = 0.f;
        }

#define DS_A(base, mh) do {                                               \
        _Pragma("unroll") for (int i_ = 0; i_ < 4; i_++) {                \
            const u16* p_ = (base) + ((mh) * 64 + i_ * 16) * 64;          \
            aF[i_][0] = *(const bf16x8*)(p_ + c0);                        \
            aF[i_][1] = *(const bf16x8*)(p_ + c1);                        \
        } } while (0)
#define DS_B(base, nh, arr) do {                                          \
        _Pragma("unroll") for (int j_ = 0; j_ < 2; j_++) {                \
            const u16* p_ = (base) + ((nh) * 32 + j_ * 16) * 64;          \
            arr[j_][0] = *(const bf16x8*)(p_ + c0);                       \
            arr[j_][1] = *(const bf16x8*)(p_ + c1);                       \
        } } while (0)
#define MFMA_Q(mh, nh, arr) do {                                          \
        __builtin_amdgcn_s_setprio(1);                                    \
        _Pragma("unroll") for (int i_ = 0; i_ < 4; i_++)                  \
        _Pragma("unroll") for (int j_ = 0; j_ < 2; j_++) {                \
            f32x4 v_ = acc[(mh) * 4 + i_][(nh) * 2 + j_];                 \
            v_ = __builtin_amdgcn_mfma_f32_16x16x32_bf16(                 \
                     aF[i_][0], arr[j_][0], v_, 0, 0, 0);                 \
            v_ = __builtin_amdgcn_mfma_f32_16x16x32_bf16(                 \
                     aF[i_][1], arr[j_][1], v_, 0, 0, 0);                 \
            acc[(mh) * 4 + i_][(nh) * 2 + j_] = v_;                       \
        }                                                                 \
        __builtin_amdgcn_s_setprio(0);                                    \
    } while (0)

    const int NT = K >> 6;
    const int NITER = NT >> 1;

    STAGE_A(0, 0, 0); STAGE_A(0, 1, 0); STAGE_B(0, 0, 0); STAGE_B(0, 1, 0);
    if (NT > 1) {
        STAGE_A(1, 0, 64); STAGE_B(1, 0, 64); STAGE_B(1, 1, 64);
        asm volatile("s_waitcnt vmcnt(6)" ::: "memory");
    } else {
        asm volatile("s_waitcnt vmcnt(0)" ::: "memory");
    }
    CFENCE; BARRIER; CFENCE;

    for (int it = 0; it < NITER; it++) {
        const int t = it * 2;
        const int k1 = (t + 1) * 64, k2 = (t + 2) * 64, k3 = (t + 3) * 64;

        DS_A(aRd0, 0); DS_B(bRd0, 0, bF0);
        if (t + 1 < NT) STAGE_A(1, 1, k1);
        CFENCE; BARRIER; CFENCE;
        MFMA_Q(0, 0, bF0);
        CFENCE; BARRIER; CFENCE;

        DS_B(bRd0, 1, bF1);
        if (t + 2 < NT) STAGE_A(0, 0, k2);
        CFENCE; BARRIER; CFENCE;
        MFMA_Q(0, 1, bF1);
        CFENCE; BARRIER; CFENCE;

        DS_A(aRd0, 1);
        if (t + 2 < NT) STAGE_B(0, 0, k2);
        CFENCE; BARRIER; CFENCE;
        MFMA_Q(1, 0, bF0);
        CFENCE; BARRIER; CFENCE;

        if (t + 2 < NT) STAGE_B(0, 1, k2);
        if (it + 1 == NITER) asm volatile("s_waitcnt vmcnt(0)" ::: "memory");
        else                 asm volatile("s_waitcnt vmcnt(6)" ::: "memory");
        CFENCE; BARRIER; CFENCE;
        MFMA_Q(1, 1, bF1);
        CFENCE; BARRIER; CFENCE;

        DS_A(aRd1, 0); DS_B(bRd1, 0, bF0);
        if (t + 2 < NT) STAGE_A(0, 1, k2);
        CFENCE; BARRIER; CFENCE;
        MFMA_Q(0, 0, bF0);
        CFENCE; BARRIER; CFENCE;

        DS_B(bRd1, 1, bF1);
        if (t + 3 < NT) STAGE_A(1, 0, k3);
        CFENCE; BARRIER; CFENCE;
        MFMA_Q(0, 1, bF1);
        CFENCE; BARRIER; CFENCE;

        DS_A(aRd1, 1);
        if (t + 3 < NT) STAGE_B(1, 0, k3);
        CFENCE; BARRIER; CFENCE;
        MFMA_Q(1, 0, bF0);
        CFENCE; BARRIER; CFENCE;

        if (t + 3 < NT) STAGE_B(1, 1, k3);
        if (it + 1 < NITER) asm volatile("s_waitcnt vmcnt(6)" ::: "memory");
        CFENCE; BARRIER; CFENCE;
        MFMA_Q(1, 1, bF1);
        CFENCE; BARRIER; CFENCE;
    }

#undef STAGE_A
#undef STAGE_B
#undef DS_A
#undef DS_B
#undef MFMA_Q

    // ---- vectorized epilogue: LDS-staged, coalesced dwordx4 stores ----
    // Per-wave slab: 64 rows x 68 u16 (stride 68 -> fq groups on disjoint
    // bank octets, 2 lanes/bank = conflict-free). Two chunks of 64 rows.
    // After the final barrier all LDS is free; slabs are wave-private, so
    // no further barriers are needed.
    u16* slab = &lds[0][0] + wave * 4352;        // 64*68 u16 per wave
    const long long crowT = (long long)bm * 256 + wm * 128;
    const int ccolT = bn * 256 + wn * 64;
    float bv[4];
#pragma unroll
    for (int j = 0; j < 4; j++) bv[j] = bf2f(bias[ccolT + fr + j * 16]);
    const int grl = lane >> 3;                   // 0..7 row in store group
    const int gcl = (lane & 7) * 8;              // col start (8 u16 each)
#pragma unroll
    for (int chunk = 0; chunk < 2; chunk++) {
        // scatter acc -> slab (MFMA layout): row ii*16+fq*4+r, col j*16+fr
#pragma unroll
        for (int ii = 0; ii < 4; ii++) {
            const int i = chunk * 4 + ii;
#pragma unroll
            for (int r = 0; r < 4; r++) {
                const int lr = ii * 16 + fq * 4 + r;
#pragma unroll
                for (int j = 0; j < 4; j++)
                    slab[lr * 68 + j * 16 + fr] =
                        f2bf(acc[i][j][r] * scale + bv[j]);
            }
        }
        CFENCE;
        // gather + coalesced store: 8 insts x (8 rows x 128B)
#pragma unroll
        for (int k = 0; k < 8; k++) {
            const int lr = k * 8 + grl;
            const bf16x8 v = *(const bf16x8*)(slab + lr * 68 + gcl);
            *(bf16x8*)(C + (crowT + chunk * 64 + lr) * (long long)ldc
                       + ccolT + gcl) = v;
        }
        CFENCE;
    }
}

// ---------------------------------------------------------------------------
// In-place row softmax over 1024 bf16 elements. One wave per row.
// ---------------------------------------------------------------------------
__global__ __launch_bounds__(256) void softmax_kernel(u16* __restrict__ S)
{
    const int tid = threadIdx.x, lane = tid & 63, wave = tid >> 6;
    const long long row = (long long)blockIdx.x * 4 + wave;
    u16* p = S + row * 1024 + lane * 16;
    union { uint4 q[2]; u16 u[16]; } d;
    d.q[0] = *(const uint4*)p;
    d.q[1] = *(const uint4*)(p + 8);
    float x[16];
    float mx = -1e30f;
#pragma unroll
    for (int j = 0; j < 16; j++) { x[j] = bf2f(d.u[j]); mx = fmaxf(mx, x[j]); }
#pragma unroll
    for (int m = 1; m < 64; m <<= 1) mx = fmaxf(mx, __shfl_xor(mx, m));
    float s = 0.f;
#pragma unroll
    for (int j = 0; j < 16; j++) { x[j] = __expf(x[j] - mx); s += x[j]; }
#pragma unroll
    for (int m = 1; m < 64; m <<= 1) s += __shfl_xor(s, m);
    const float inv = 1.0f / s;
#pragma unroll
    for (int j = 0; j < 16; j++) d.u[j] = f2bf(x[j] * inv);
    *(uint4*)p = d.q[0];
    *(uint4*)(p + 8) = d.q[1];
}

// ---------------------------------------------------------------------------
// LayerNorm(obj + I) * g + b -> out. One block per row (objMask variant).
// ---------------------------------------------------------------------------
__global__ __launch_bounds__(256) void ln_kernel(
    const u16* __restrict__ obj, const u16* __restrict__ gam,
    const u16* __restrict__ bet, const u16* __restrict__ I,
    void* __restrict__ outv, long long outOff, int objMask,
    const int* __restrict__ flag)
{
    __shared__ float red[8];
    const int tid = threadIdx.x, lane = tid & 63, wave = tid >> 6;
    const long long base = (long long)blockIdx.x * 1024;
    const long long obase = (long long)(blockIdx.x & objMask) * 1024;
    const int c = tid * 4;
    union { uint2 q; u16 u[4]; } ov, iv, gv, bv;
    ov.q = *(const uint2*)(obj + obase + c);
    iv.q = *(const uint2*)(I + base + c);
    float x[4], s = 0.f, sq = 0.f;
#pragma unroll
    for (int j = 0; j < 4; j++) {
        x[j] = bf2f(ov.u[j]) + bf2f(iv.u[j]);
        s += x[j]; sq += x[j] * x[j];
    }
#pragma unroll
    for (int m = 1; m < 64; m <<= 1) {
        s += __shfl_xor(s, m);
        sq += __shfl_xor(sq, m);
    }
    if (lane == 0) { red[wave] = s; red[4 + wave] = sq; }
    __syncthreads();
    s = red[0] + red[1] + red[2] + red[3];
    sq = red[4] + red[5] + red[6] + red[7];
    const float mu = s * (1.0f / 1024.0f);
    const float var = fmaxf(sq * (1.0f / 1024.0f) - mu * mu, 0.0f);
    const float rs = rsqrtf(var + 1e-5f);
    gv.q = *(const uint2*)(gam + c);
    bv.q = *(const uint2*)(bet + c);
    float y[4];
#pragma unroll
    for (int j = 0; j < 4; j++)
        y[j] = (x[j] - mu) * rs * bf2f(gv.u[j]) + bf2f(bv.u[j]);
    if (flag[0]) {
        float4 w; w.x = y[0]; w.y = y[1]; w.z = y[2]; w.w = y[3];
        *(float4*)((float*)outv + outOff + base + c) = w;
    } else {
        union { uint2 q; u16 u[4]; } wv;
#pragma unroll
        for (int j = 0; j < 4; j++) wv.u[j] = f2bf(y[j]);
        *(uint2*)((u16*)outv + outOff + base + c) = wv.q;
    }
}

// ---------------------------------------------------------------------------
// Merged LayerNorm, BOTH sides per row: reads obj once, I1 and I2 = I+iOff,
// writes out row and out row+oOff. One block per row (16384 blocks).
// ---------------------------------------------------------------------------
__global__ __launch_bounds__(256) void ln2_kernel(
    const u16* __restrict__ obj, const u16* __restrict__ gam,
    const u16* __restrict__ bet, const u16* __restrict__ I, long long iOff,
    void* __restrict__ outv, long long oOff, const int* __restrict__ flag)
{
    __shared__ float red[16];
    const int tid = threadIdx.x, lane = tid & 63, wave = tid >> 6;
    const long long base = (long long)blockIdx.x * 1024;
    const int c = tid * 4;
    union { uint2 q; u16 u[4]; } ov, i1, i2, gv, bv;
    ov.q = *(const uint2*)(obj + base + c);
    i1.q = *(const uint2*)(I + base + c);
    i2.q = *(const uint2*)(I + iOff + base + c);
    float x1[4], x2[4], s1 = 0.f, q1 = 0.f, s2 = 0.f, q2 = 0.f;
#pragma unroll
    for (int j = 0; j < 4; j++) {
        const float o = bf2f(ov.u[j]);
        x1[j] = o + bf2f(i1.u[j]);
        x2[j] = o + bf2f(i2.u[j]);
        s1 += x1[j]; q1 += x1[j] * x1[j];
        s2 += x2[j]; q2 += x2[j] * x2[j];
    }
#pragma unroll
    for (int m = 1; m < 64; m <<= 1) {
        s1 += __shfl_xor(s1, m); q1 += __shfl_xor(q1, m);
        s2 += __shfl_xor(s2, m); q2 += __shfl_xor(q2, m);
    }
    if (lane == 0) {
        red[wave] = s1; red[4 + wave] = q1;
        red[8 + wave] = s2; red[12 + wave] = q2;
    }
    __syncthreads();
    s1 = red[0] + red[1] + red[2] + red[3];
    q1 = red[4] + red[5] + red[6] + red[7];
    s2 = red[8] + red[9] + red[10] + red[11];
    q2 = red[12] + red[13] + red[14] + red[15];
    const float mu1 = s1 * (1.0f / 1024.0f);
    const float rs1 = rsqrtf(fmaxf(q1 * (1.0f / 1024.0f) - mu1 * mu1, 0.0f)
                             + 1e-5f);
    const float mu2 = s2 * (1.0f / 1024.0f);
    const float rs2 = rsqrtf(fmaxf(q2 * (1.0f / 1024.0f) - mu2 * mu2, 0.0f)
                             + 1e-5f);
    gv.q = *(const uint2*)(gam + c);
    bv.q = *(const uint2*)(bet + c);
    float y1[4], y2[4];
#pragma unroll
    for (int j = 0; j < 4; j++) {
        const float g = bf2f(gv.u[j]), b = bf2f(bv.u[j]);
        y1[j] = (x1[j] - mu1) * rs1 * g + b;
        y2[j] = (x2[j] - mu2) * rs2 * g + b;
    }
    if (flag[0]) {
        float4 w1, w2;
        w1.x = y1[0]; w1.y = y1[1]; w1.z = y1[2]; w1.w = y1[3];
        w2.x = y2[0]; w2.y = y2[1]; w2.z = y2[2]; w2.w = y2[3];
        *(float4*)((float*)outv + base + c) = w1;
        *(float4*)((float*)outv + oOff + base + c) = w2;
    } else {
        union { uint2 q; u16 u[4]; } w1, w2;
#pragma unroll
        for (int j = 0; j < 4; j++) { w1.u[j] = f2bf(y1[j]); w2.u[j] = f2bf(y2[j]); }
        *(uint2*)((u16*)outv + base + c) = w1.q;
        *(uint2*)((u16*)outv + oOff + base + c) = w2.q;
    }
}

// ---------------------------------------------------------------------------
extern "C" void kernel_launch(void* const* d_in, const int* in_sizes, int n_in,
                              void* d_out, int out_size, void* d_ws, size_t ws_size,
                              hipStream_t stream)
{
    u16* ws = (u16*)d_ws;
    int* flag = (int*)d_ws;              // header: first 64 bytes
    const dim3 blk(256);
    const dim3 blk5(512);
    const float scale = 0.03125f;        // 1024^-0.5
    const long long Eobj = 16777216;     // 8*2048*1024
    const long long Ekv  = 8388608;      // 8*1024*1024
    const long long sQ = 2048LL * 1024, sK = 1024LL * 1024;
    const int ALLZ = 255;                // zAmask: full z indexing
    const int NOZ = -1;                  // zShift: use blockIdx.z

    detect_kernel<<<dim3(1), blk, 0, stream>>>((const u16*)d_in[0], flag);

    // merged conversion into contiguous region after 64B header
    const size_t wsElems = ws_size / 2;
    ConvArgs ca;
    long long cur = 32;
    u16* cIn[15];
    for (int i = 0; i < 15; i++) {
        ca.src[i] = d_in[i];
        ca.off[i] = cur - 32;
        cIn[i] = ws + cur;
        cur += in_sizes[i];
    }
    ca.off[15] = cur - 32;
    const long long convTotal = cur - 32;
    const bool canConv = wsElems >= (size_t)(32 + convTotal + 8388608 + 32);
    if (canConv) {
        const int grid = (int)((convTotal / 8 + 255) / 256);
        convert_all_kernel<<<dim3(grid), blk, 0, stream>>>(ca, ws + 32, flag);
    } else {
        for (int i = 0; i < 15; i++) cIn[i] = (u16*)d_in[i];
        cur = 32;
    }
    const u16* obj = cIn[0];  const u16* sub = cIn[1];  const u16* scene = cIn[2];
    const u16* W_q = cIn[3];  const u16* b_q = cIn[4];
    const u16* W_sk = cIn[5]; const u16* b_sk = cIn[6];
    const u16* W_sv = cIn[7]; const u16* b_sv = cIn[8];
    const u16* W_ek = cIn[9]; const u16* b_ek = cIn[10];
    const u16* W_ev = cIn[11]; const u16* b_ev = cIn[12];
    const u16* ln_g = cIn[13]; const u16* ln_b = cIn[14];

    // planMerged: both attention sides in single dispatches (S,O doubled)
    const bool planMerged = canConv &&
        wsElems >= (size_t)(cur + 5 * Eobj + 4 * Ekv);
    const bool planComb = canConv &&
        wsElems >= (size_t)(cur + 3 * Eobj + 4 * Ekv);
    const bool planA = wsElems >= (size_t)(cur + 3 * Eobj + 2 * Ekv);

    if (planMerged) {
        u16* Q  = ws + cur;          // Eobj      (contiguous with Kb below)
        u16* Kb = Q + Eobj;          // 2*Ekv : [a][z][1024][1024]
        u16* VT = Kb + 2 * Ekv;      // 2*Ekv : VT[p][a*8192 + z*1024 + s]
        u16* S  = VT + 2 * Ekv;      // 2*Eobj: [a][z][2048][1024]
        u16* O  = S + 2 * Eobj;      // 2*Eobj

        // Merged Q+K projection: A = [obj;sub;scene] (contiguous, 32768 rows),
        // C = [Q;Kb] (contiguous), 3-way W select by bm (64/96 of nbm=128).
        gemm256p3_kernel<<<dim3(512, 1, 1), blk5, 0, stream>>>(
            obj, W_q, Q, b_q, W_sk, b_sk, W_ek, b_ek,
            1.0f, 2, 1024, 1024, 1024, 1024);
        // VT[p][n] = {W_sv|W_ev}[p,:] . [sub;scene][n,:] + bias (dual bn)
        gemm256_kernel<<<dim3(256, 1, 1), blk5, 0, stream>>>(
            W_sv, sub, VT, b_sv, W_ev, b_ev,
            1.0f, 2, 2, 6, ALLZ, NOZ, 1024, 1024, 16384, 1024, 0, 0, 0);

        // S[a][z] = Q[z] . Kb[a][z]^T : flattened z'=id>>5, A indexed z'&7
        gemm256_kernel<<<dim3(512, 1, 1), blk5, 0, stream>>>(
            Q, Kb, S, nullptr, nullptr, nullptr,
            scale, 0, 0, 2, 7, 5, 1024, 1024, 1024, 1024, sQ, sK, sQ);
        softmax_kernel<<<dim3(8192), blk, 0, stream>>>(S);
        // O[a][z] = S[a][z] . V; VT col offset z'*1024
        gemm256_kernel<<<dim3(512, 1, 1), blk5, 0, stream>>>(
            S, VT, O, nullptr, nullptr, nullptr,
            1.0f, 0, 0, 2, ALLZ, 5, 1024, 16384, 1024, 1024, sQ, 1024, sQ);
        // Merged LN: both sides per row, obj read once
        ln2_kernel<<<dim3(16384), blk, 0, stream>>>(
            obj, ln_g, ln_b, O, Eobj, d_out, Eobj, flag);
    } else if (planComb) {
        u16* Q  = ws + cur;          // Eobj
        u16* Kb = Q + Eobj;          // 2*Ekv
        u16* VT = Kb + 2 * Ekv;      // 2*Ekv
        u16* S  = VT + 2 * Ekv;      // Eobj
        u16* O  = S + Eobj;          // Eobj

        gemm256p3_kernel<<<dim3(512, 1, 1), blk5, 0, stream>>>(
            obj, W_q, Q, b_q, W_sk, b_sk, W_ek, b_ek,
            1.0f, 2, 1024, 1024, 1024, 1024);
        gemm256_kernel<<<dim3(256, 1, 1), blk5, 0, stream>>>(
            W_sv, sub, VT, b_sv, W_ev, b_ev,
            1.0f, 2, 2, 6, ALLZ, NOZ, 1024, 1024, 16384, 1024, 0, 0, 0);

        for (int a = 0; a < 2; a++) {
            gemm256_kernel<<<dim3(32, 1, 8), blk5, 0, stream>>>(
                Q, Kb + (long long)a * Ekv, S, nullptr, nullptr, nullptr,
                scale, 0, 0, 2, ALLZ, NOZ, 1024, 1024, 1024, 1024, sQ, sK, sQ);
            softmax_kernel<<<dim3(4096), blk, 0, stream>>>(S);
            gemm256_kernel<<<dim3(32, 1, 8), blk5, 0, stream>>>(
                S, VT + a * 8192, O, nullptr, nullptr, nullptr,
                1.0f, 0, 0, 2, ALLZ, NOZ, 1024, 16384, 1024, 1024, sQ, 1024, sQ);
            ln_kernel<<<dim3(16384), blk, 0, stream>>>(
                obj, ln_g, ln_b, O, d_out, (long long)a * Eobj, 0x7fffffff,
                flag);
        }
    } else if (planA) {
        u16* Q  = ws + cur;
        u16* Kb = Q + Eobj;
        u16* VT = Kb + Ekv;
        u16* S  = VT + Ekv;
        u16* O  = S + Eobj;

        gemm256_kernel<<<dim3(256, 1, 1), blk5, 0, stream>>>(
            obj, W_q, Q, b_q, nullptr, nullptr,
            1.0f, 1, 0, 2, ALLZ, NOZ, 1024, 1024, 1024, 1024, 0, 0, 0);

        for (int a = 0; a < 2; a++) {
            const u16* X  = a ? scene : sub;
            const u16* Wk = a ? W_ek : W_sk;
            const u16* bk = a ? b_ek : b_sk;
            const u16* Wv = a ? W_ev : W_sv;
            const u16* bv = a ? b_ev : b_sv;

            gemm256_kernel<<<dim3(128, 1, 1), blk5, 0, stream>>>(
                X, Wk, Kb, bk, nullptr, nullptr,
                1.0f, 1, 0, 2, ALLZ, NOZ, 1024, 1024, 1024, 1024, 0, 0, 0);
            gemm256_kernel<<<dim3(128, 1, 1), blk5, 0, stream>>>(
                Wv, X, VT, bv, nullptr, nullptr,
                1.0f, 2, 0, 5, ALLZ, NOZ, 1024, 1024, 8192, 1024, 0, 0, 0);
            gemm256_kernel<<<dim3(32, 1, 8), blk5, 0, stream>>>(
                Q, Kb, S, nullptr, nullptr, nullptr,
                scale, 0, 0, 2, ALLZ, NOZ, 1024, 1024, 1024, 1024, sQ, sK, sQ);
            softmax_kernel<<<dim3(4096), blk, 0, stream>>>(S);
            gemm256_kernel<<<dim3(32, 1, 8), blk5, 0, stream>>>(
                S, VT, O, nullptr, nullptr, nullptr,
                1.0f, 0, 0, 2, ALLZ, NOZ, 1024, 8192, 1024, 1024, sQ, 1024, sQ);
            ln_kernel<<<dim3(16384), blk, 0, stream>>>(
                obj, ln_g, ln_b, O, d_out, (long long)a * Eobj, 0x7fffffff,
                flag);
        }
    } else {
        // per-batch fallback: 8.39M elems of pipeline scratch
        u16* Qb = ws + cur;              // 2M
        u16* Kb = Qb + 2097152;          // 1M
        u16* VT = Kb + 1048576;          // 1M
        u16* S  = VT + 1048576;          // 2M
        u16* O  = S + 2097152;           // 2M

        for (int a = 0; a < 2; a++) {
            const u16* X  = a ? scene : sub;
            const u16* Wk = a ? W_ek : W_sk;
            const u16* bk = a ? b_ek : b_sk;
            const u16* Wv = a ? W_ev : W_sv;
            const u16* bv = a ? b_ev : b_sv;

            for (int z = 0; z < 8; z++) {
                const u16* objz = obj + (long long)z * sQ;
                const u16* Xz   = X + (long long)z * sK;
                gemm256_kernel<<<dim3(32, 1, 1), blk5, 0, stream>>>(
                    objz, W_q, Qb, b_q, nullptr, nullptr,
                    1.0f, 1, 0, 2, ALLZ, NOZ, 1024, 1024, 1024, 1024, 0, 0, 0);
                gemm256_kernel<<<dim3(16, 1, 1), blk5, 0, stream>>>(
                    Xz, Wk, Kb, bk, nullptr, nullptr,
                    1.0f, 1, 0, 2, ALLZ, NOZ, 1024, 1024, 1024, 1024, 0, 0, 0);
                gemm256_kernel<<<dim3(16, 1, 1), blk5, 0, stream>>>(
                    Wv, Xz, VT, bv, nullptr, nullptr,
                    1.0f, 2, 0, 2, ALLZ, NOZ, 1024, 1024, 1024, 1024, 0, 0, 0);
                gemm256_kernel<<<dim3(32, 1, 1), blk5, 0, stream>>>(
                    Qb, Kb, S, nullptr, nullptr, nullptr,
                    scale, 0, 0, 2, ALLZ, NOZ, 1024, 1024, 1024, 1024, 0, 0, 0);
                softmax_kernel<<<dim3(512), blk, 0, stream>>>(S);
                gemm256_kernel<<<dim3(32, 1, 1), blk5, 0, stream>>>(
                    S, VT, O, nullptr, nullptr, nullptr,
                    1.0f, 0, 0, 2, ALLZ, NOZ, 1024, 1024, 1024, 1024, 0, 0, 0);
                ln_kernel<<<dim3(2048), blk, 0, stream>>>(
                    objz, ln_g, ln_b, O, d_out,
                    (long long)a * Eobj + (long long)z * sQ, 0x7fffffff,
                    flag);
            }
        }
    }

    (void)n_in; (void)out_size;
}